// Round 3
// baseline (317.448 us; speedup 1.0000x reference)
//
#include <hip/hip_runtime.h>

// SelfAttention3d: B=4, C=128, D=16, H=W=64.
// Pipeline (bf16 MFMA, f32 accum/softmax):
//   K1 qkv   : q -> ws, k -> d_out[0:64M], v -> d_out[64M:128M]   (bf16)
//              X kept in register B-fragments (shared across q/k/v GEMMs);
//              LDS holds only W (32KB) + biases -> 3-4 WG/CU.
//   K2 attn  : per (b,c,d) 64x64 slice, O -> ws (in-place over q)
//   K3 tail  : a1+relu -> a2 -> f fused via LDS round-trips, f32 -> d_out

#define CCH 128
#define SPB 65536      // per-batch spatial = D*H*W
#define NBATCH 4

typedef float f32x4 __attribute__((ext_vector_type(4)));
typedef __bf16 bf16x8 __attribute__((ext_vector_type(8)));
typedef short s16x8 __attribute__((ext_vector_type(8)));
typedef unsigned short u16x8 __attribute__((ext_vector_type(8)));

// ---- MFMA wrapper: robust to builtin signature (v8i16 vs v8bf16) ----
template <typename T>
static __device__ __forceinline__ auto mfma_try(T a, T b, f32x4 c, int)
    -> decltype(__builtin_amdgcn_mfma_f32_16x16x32_bf16(a, b, c, 0, 0, 0)) {
  return __builtin_amdgcn_mfma_f32_16x16x32_bf16(a, b, c, 0, 0, 0);
}
template <typename T>
static __device__ __forceinline__ f32x4 mfma_try(T a, T b, f32x4 c, long) {
  return __builtin_amdgcn_mfma_f32_16x16x32_bf16(
      __builtin_bit_cast(bf16x8, a), __builtin_bit_cast(bf16x8, b), c, 0, 0, 0);
}
static __device__ __forceinline__ f32x4 MFMA16(u16x8 a, u16x8 b, f32x4 c) {
  return mfma_try(__builtin_bit_cast(s16x8, a), __builtin_bit_cast(s16x8, b), c, 0);
}

// f32 -> bf16 bits, round-to-nearest-even
static __device__ __forceinline__ unsigned short f2b(float f) {
  unsigned int u = __builtin_bit_cast(unsigned int, f);
  u += 0x7FFFu + ((u >> 16) & 1u);
  return (unsigned short)(u >> 16);
}

// W swizzle for 128-col bf16 rows: slot=(c>>3)^(m&15). Bijective per row;
// 16-row fragment reads and 32-row staged writes are bank-quad-even.
static __device__ __forceinline__ int swzw(int m, int c) {
  int slot = ((c >> 3) ^ (m & 15)) & 15;
  return m * 128 + slot * 8 + (c & 7);
}
// Legacy swizzles (tail/attn kernels, unchanged from round 2).
static __device__ __forceinline__ int swzc(int r, int c) {
  int slot = ((c >> 3) ^ (r & 7) ^ ((r >> 3) & 15)) & 15;
  return r * 128 + slot * 8 + (c & 7);
}
static __device__ __forceinline__ int swza(int r, int c) {
  int slot = ((c >> 3) ^ (r & 7)) & 7;
  return r * 64 + slot * 8 + (c & 7);
}

// ---------------------------------------------------------------------------
// K1: fused QKV conv. M=128(out-ch) x N=128(spatial) x K=128(in-ch) per WG.
// X B-fragments live in registers (loaded once, used by all 3 convs); only W
// is staged in LDS. 256 thr / 4 waves; wave wv owns s-cols [wv*32, wv*32+32).
// ---------------------------------------------------------------------------
__global__ __launch_bounds__(256, 3) void qkv_kernel(
    const float* __restrict__ X,
    const float* __restrict__ Wq, const float* __restrict__ Bq, unsigned short* __restrict__ Yq,
    const float* __restrict__ Wk, const float* __restrict__ Bk, unsigned short* __restrict__ Yk,
    const float* __restrict__ Wv, const float* __restrict__ Bv, unsigned short* __restrict__ Yv)
{
  __shared__ unsigned short w_lds[128 * 128];   // W[o][c], swzw layout
  __shared__ float bias_lds[3][128];

  const int tid  = threadIdx.x;
  const int wv   = tid >> 6;
  const int lane = tid & 63;
  const int lr   = lane & 15;
  const int lg   = lane >> 4;
  const int s0   = blockIdx.x * 128;
  const size_t xbase = (size_t)blockIdx.y * CCH * SPB;

  if (tid < 128) {
    bias_lds[0][tid] = Bq[tid];
    bias_lds[1][tid] = Bk[tid];
    bias_lds[2][tid] = Bv[tid];
  }

  // ---- load X B-fragments straight to registers (no LDS, no barrier) ----
  // Fragment (nf,ks): lane holds X^T[s = s0+wv*32+nf*16+lr][c = ks*32+lg*8 .. +8].
  u16x8 bfr[2][4];
  {
    const float* xs = X + xbase + s0 + wv * 32 + lr;
#pragma unroll
    for (int nf = 0; nf < 2; ++nf)
#pragma unroll
      for (int ks = 0; ks < 4; ++ks) {
        const float* xp = xs + (size_t)(ks * 32 + lg * 8) * SPB + nf * 16;
        float xr[8];
#pragma unroll
        for (int i = 0; i < 8; ++i) xr[i] = xp[(size_t)i * SPB];
        u16x8 u;
#pragma unroll
        for (int i = 0; i < 8; ++i) u[i] = f2b(xr[i]);
        bfr[nf][ks] = u;
      }
  }

  auto do_conv = [&](const float* __restrict__ W, int ci,
                     unsigned short* __restrict__ Y) {
    __syncthreads();  // previous conv's w_lds reads done (and bias staged)
    {
      const int m  = tid >> 1;
      const int hh = (tid & 1) * 64;
#pragma unroll
      for (int p = 0; p < 8; ++p) {
        const int c0 = hh + p * 8;
        f32x4 a = *(const f32x4*)&W[m * 128 + c0];
        f32x4 b = *(const f32x4*)&W[m * 128 + c0 + 4];
        u16x8 u;
#pragma unroll
        for (int i = 0; i < 4; ++i) { u[i] = f2b(a[i]); u[4 + i] = f2b(b[i]); }
        *(u16x8*)&w_lds[swzw(m, c0)] = u;
      }
    }
    __syncthreads();

    f32x4 acc[8][2];
#pragma unroll
    for (int mf = 0; mf < 8; ++mf)
#pragma unroll
      for (int nf = 0; nf < 2; ++nf) {
        f32x4 z = {0.f, 0.f, 0.f, 0.f};
        acc[mf][nf] = z;
      }

#pragma unroll
    for (int ks = 0; ks < 4; ++ks) {
      const int k0 = ks * 32 + lg * 8;
#pragma unroll
      for (int mf = 0; mf < 8; ++mf) {
        u16x8 afr = *(const u16x8*)&w_lds[swzw(mf * 16 + lr, k0)];
        acc[mf][0] = MFMA16(afr, bfr[0][ks], acc[mf][0]);
        acc[mf][1] = MFMA16(afr, bfr[1][ks], acc[mf][1]);
      }
    }

#pragma unroll
    for (int mf = 0; mf < 8; ++mf)
#pragma unroll
      for (int nf = 0; nf < 2; ++nf)
#pragma unroll
        for (int r = 0; r < 4; ++r) {
          const int o = mf * 16 + lg * 4 + r;
          const int s = s0 + wv * 32 + nf * 16 + lr;
          Y[xbase + (size_t)o * SPB + s] = f2b(acc[mf][nf][r] + bias_lds[ci][o]);
        }
  };

  do_conv(Wq, 0, Yq);
  do_conv(Wk, 1, Yk);
  do_conv(Wv, 2, Yv);
}

// ---------------------------------------------------------------------------
// K2: attention over one (b,c,d) slice. S = Q^T K (contract h), softmax_j,
// O = P V. 1 WG (4 waves) per slice; wave wv owns rows [wv*16, wv*16+16).
// (unchanged from round 2)
// ---------------------------------------------------------------------------
__global__ __launch_bounds__(256) void attn64_kernel(
    const unsigned short* __restrict__ Q,
    const unsigned short* __restrict__ K,
    const unsigned short* __restrict__ V,
    unsigned short* __restrict__ O)
{
  __shared__ unsigned short qt[64 * 64];      // Q^T[w][x]
  __shared__ unsigned short kt[64 * 64];      // K^T[w][x]
  __shared__ unsigned short vt[64 * 64];      // V^T[w][x]
  __shared__ unsigned short p_lds[4][16 * 64];

  const int tid  = threadIdx.x;
  const int wv   = tid >> 6;
  const int lane = tid & 63;
  const int lr   = lane & 15;
  const int lg   = lane >> 4;
  const size_t base = (size_t)blockIdx.x * 4096;

  {
    const int w0 = (tid & 31) * 2;   // two w-columns per thread
    const int x0 = (tid >> 5) * 8;   // eight x-rows per thread
    unsigned int qv[8], kv[8], vv[8];
#pragma unroll
    for (int i = 0; i < 8; ++i) {
      const size_t g = base + (size_t)(x0 + i) * 64 + w0;
      qv[i] = *(const unsigned int*)&Q[g];
      kv[i] = *(const unsigned int*)&K[g];
      vv[i] = *(const unsigned int*)&V[g];
    }
#pragma unroll
    for (int p = 0; p < 2; ++p) {
      u16x8 uq, uk, uv;
#pragma unroll
      for (int i = 0; i < 8; ++i) {
        uq[i] = (unsigned short)(qv[i] >> (16 * p));
        uk[i] = (unsigned short)(kv[i] >> (16 * p));
        uv[i] = (unsigned short)(vv[i] >> (16 * p));
      }
      *(u16x8*)&qt[swza(w0 + p, x0)] = uq;
      *(u16x8*)&kt[swza(w0 + p, x0)] = uk;
      *(u16x8*)&vt[swza(w0 + p, x0)] = uv;
    }
  }
  __syncthreads();

  f32x4 sacc[4];
#pragma unroll
  for (int nf = 0; nf < 4; ++nf) { f32x4 z = {0.f, 0.f, 0.f, 0.f}; sacc[nf] = z; }
#pragma unroll
  for (int ks = 0; ks < 2; ++ks) {
    const int k0 = ks * 32 + lg * 8;
    u16x8 a = *(const u16x8*)&qt[swza(wv * 16 + lr, k0)];
#pragma unroll
    for (int nf = 0; nf < 4; ++nf) {
      u16x8 bb = *(const u16x8*)&kt[swza(nf * 16 + lr, k0)];
      sacc[nf] = MFMA16(a, bb, sacc[nf]);
    }
  }

#pragma unroll
  for (int r = 0; r < 4; ++r) {
    float m = fmaxf(fmaxf(sacc[0][r], sacc[1][r]), fmaxf(sacc[2][r], sacc[3][r]));
    m = fmaxf(m, __shfl_xor(m, 1));
    m = fmaxf(m, __shfl_xor(m, 2));
    m = fmaxf(m, __shfl_xor(m, 4));
    m = fmaxf(m, __shfl_xor(m, 8));
    float sum = 0.f;
#pragma unroll
    for (int nf = 0; nf < 4; ++nf) {
      float p = __expf(sacc[nf][r] - m);
      sacc[nf][r] = p;
      sum += p;
    }
    sum += __shfl_xor(sum, 1);
    sum += __shfl_xor(sum, 2);
    sum += __shfl_xor(sum, 4);
    sum += __shfl_xor(sum, 8);
    const float inv = 1.f / sum;
#pragma unroll
    for (int nf = 0; nf < 4; ++nf)
      p_lds[wv][swza(lg * 4 + r, nf * 16 + lr)] = f2b(sacc[nf][r] * inv);
  }

  f32x4 oacc[4];
#pragma unroll
  for (int nf = 0; nf < 4; ++nf) { f32x4 z = {0.f, 0.f, 0.f, 0.f}; oacc[nf] = z; }
#pragma unroll
  for (int ks = 0; ks < 2; ++ks) {
    const int k0 = ks * 32 + lg * 8;
    u16x8 a = *(const u16x8*)&p_lds[wv][swza(lr, k0)];
#pragma unroll
    for (int nf = 0; nf < 4; ++nf) {
      u16x8 bb = *(const u16x8*)&vt[swza(nf * 16 + lr, k0)];
      oacc[nf] = MFMA16(a, bb, oacc[nf]);
    }
  }
#pragma unroll
  for (int nf = 0; nf < 4; ++nf)
#pragma unroll
    for (int r = 0; r < 4; ++r)
      O[base + (size_t)(wv * 16 + lg * 4 + r) * 64 + nf * 16 + lr] = f2b(oacc[nf][r]);
}

// ---------------------------------------------------------------------------
// K3: fused tail a1+relu -> a2 -> f (unchanged from round 2).
// ---------------------------------------------------------------------------
__global__ __launch_bounds__(256) void tail_kernel(
    const unsigned short* __restrict__ Xb,
    const float* __restrict__ W1, const float* __restrict__ B1,
    const float* __restrict__ W2, const float* __restrict__ B2,
    const float* __restrict__ W3, const float* __restrict__ B3,
    float* __restrict__ OUT)
{
  __shared__ unsigned short w_lds[128 * 128];
  __shared__ unsigned short xt_lds[128 * 128];
  __shared__ float bias_lds[128];

  const int tid  = threadIdx.x;
  const int wv   = tid >> 6;
  const int lane = tid & 63;
  const int lr   = lane & 15;
  const int lg   = lane >> 4;
  const int s0   = blockIdx.x * 128;
  const size_t xbase = (size_t)blockIdx.y * CCH * SPB;

  {
    const int c0  = (tid >> 4) * 8;
    const int sl0 = (tid & 15) * 8;
    const unsigned short* Xp = Xb + xbase + s0 + sl0;
    u16x8 xr[8];
#pragma unroll
    for (int i = 0; i < 8; ++i)
      xr[i] = *(const u16x8*)&Xp[(size_t)(c0 + i) * SPB];
#pragma unroll
    for (int j = 0; j < 8; ++j) {
      u16x8 u;
#pragma unroll
      for (int i = 0; i < 8; ++i) u[i] = xr[i][j];
      *(u16x8*)&xt_lds[swzc(sl0 + j, c0)] = u;
    }
  }

  auto do_gemm = [&](const float* __restrict__ W, const float* __restrict__ Bb,
                     bool relu, bool to_lds) {
    __syncthreads();
    {
      const int m  = tid >> 1;
      const int hh = (tid & 1) * 64;
#pragma unroll
      for (int p = 0; p < 8; ++p) {
        const int c0 = hh + p * 8;
        f32x4 a = *(const f32x4*)&W[m * 128 + c0];
        f32x4 b = *(const f32x4*)&W[m * 128 + c0 + 4];
        u16x8 u;
#pragma unroll
        for (int i = 0; i < 4; ++i) { u[i] = f2b(a[i]); u[4 + i] = f2b(b[i]); }
        *(u16x8*)&w_lds[swzc(m, c0)] = u;
      }
      if (tid < 128) bias_lds[tid] = Bb[tid];
    }
    __syncthreads();

    f32x4 acc[8][2];
#pragma unroll
    for (int mf = 0; mf < 8; ++mf)
#pragma unroll
      for (int nf = 0; nf < 2; ++nf) {
        f32x4 z = {0.f, 0.f, 0.f, 0.f};
        acc[mf][nf] = z;
      }

#pragma unroll
    for (int ks = 0; ks < 4; ++ks) {
      const int k0 = ks * 32 + lg * 8;
      u16x8 bfr[2];
#pragma unroll
      for (int nf = 0; nf < 2; ++nf)
        bfr[nf] = *(const u16x8*)&xt_lds[swzc(wv * 32 + nf * 16 + lr, k0)];
#pragma unroll
      for (int mf = 0; mf < 8; ++mf) {
        u16x8 afr = *(const u16x8*)&w_lds[swzc(mf * 16 + lr, k0)];
        acc[mf][0] = MFMA16(afr, bfr[0], acc[mf][0]);
        acc[mf][1] = MFMA16(afr, bfr[1], acc[mf][1]);
      }
    }

#pragma unroll
    for (int mf = 0; mf < 8; ++mf)
#pragma unroll
      for (int nf = 0; nf < 2; ++nf)
#pragma unroll
        for (int r = 0; r < 4; ++r) {
          const int o  = mf * 16 + lg * 4 + r;
          const int sl = wv * 32 + nf * 16 + lr;
          float val = acc[mf][nf][r] + bias_lds[o];
          if (relu) val = fmaxf(val, 0.f);
          if (to_lds)
            xt_lds[swzc(sl, o)] = f2b(val);   // wave-private rows of xt
          else
            OUT[xbase + (size_t)o * SPB + s0 + sl] = val;
        }
  };

  do_gemm(W1, B1, true,  true);
  do_gemm(W2, B2, false, true);
  do_gemm(W3, B3, false, false);
}

extern "C" void kernel_launch(void* const* d_in, const int* in_sizes, int n_in,
                              void* d_out, int out_size, void* d_ws, size_t ws_size,
                              hipStream_t stream) {
  const float* x   = (const float*)d_in[0];
  const float* Wq  = (const float*)d_in[1];  const float* bq  = (const float*)d_in[2];
  const float* Wk  = (const float*)d_in[3];  const float* bk  = (const float*)d_in[4];
  const float* Wv  = (const float*)d_in[5];  const float* bv  = (const float*)d_in[6];
  const float* Wa1 = (const float*)d_in[7];  const float* ba1 = (const float*)d_in[8];
  const float* Wa2 = (const float*)d_in[9];  const float* ba2 = (const float*)d_in[10];
  const float* Wf  = (const float*)d_in[11]; const float* bf_ = (const float*)d_in[12];

  // bf16 scratch: q in ws; k,v packed into d_out (dead before final f32 write).
  unsigned short* qb = (unsigned short*)d_ws;
  unsigned short* kb = (unsigned short*)d_out;
  unsigned short* vb = kb + (size_t)NBATCH * CCH * SPB;

  dim3 grid(SPB / 128, NBATCH);

  qkv_kernel<<<grid, 256, 0, stream>>>(x, Wq, bq, qb, Wk, bk, kb, Wv, bv, vb);

  attn64_kernel<<<NBATCH * CCH * 16, 256, 0, stream>>>(qb, kb, vb, qb);

  tail_kernel<<<grid, 256, 0, stream>>>(qb, Wa1, ba1, Wa2, ba2, Wf, bf_,
                                        (float*)d_out);
}

// Round 4
// 289.291 us; speedup vs baseline: 1.0973x; 1.0973x over previous
//
#include <hip/hip_runtime.h>

// SelfAttention3d: B=4, C=128, D=16, H=W=64.
// All global traffic 16B-vectorized; transposes go through LDS scalar ops.
//   K1 qkv   : q -> ws, k -> d_out[0:64M], v -> d_out[64M:128M]   (bf16)
//   K2 attn  : per (b,c,d) 64x64 slice, O -> ws (in-place over q)
//   K3 tail  : a1+relu -> a2 -> f chained in LDS, f32 -> d_out

#define CCH 128
#define SPB 65536      // per-batch spatial = D*H*W
#define NBATCH 4

typedef float f32x4 __attribute__((ext_vector_type(4)));
typedef __bf16 bf16x8 __attribute__((ext_vector_type(8)));
typedef short s16x8 __attribute__((ext_vector_type(8)));
typedef unsigned short u16x8 __attribute__((ext_vector_type(8)));

// ---- MFMA wrapper: robust to builtin signature (v8i16 vs v8bf16) ----
template <typename T>
static __device__ __forceinline__ auto mfma_try(T a, T b, f32x4 c, int)
    -> decltype(__builtin_amdgcn_mfma_f32_16x16x32_bf16(a, b, c, 0, 0, 0)) {
  return __builtin_amdgcn_mfma_f32_16x16x32_bf16(a, b, c, 0, 0, 0);
}
template <typename T>
static __device__ __forceinline__ f32x4 mfma_try(T a, T b, f32x4 c, long) {
  return __builtin_amdgcn_mfma_f32_16x16x32_bf16(
      __builtin_bit_cast(bf16x8, a), __builtin_bit_cast(bf16x8, b), c, 0, 0, 0);
}
static __device__ __forceinline__ f32x4 MFMA16(u16x8 a, u16x8 b, f32x4 c) {
  return mfma_try(__builtin_bit_cast(s16x8, a), __builtin_bit_cast(s16x8, b), c, 0);
}

// f32 -> bf16 bits, round-to-nearest-even
static __device__ __forceinline__ unsigned short f2b(float f) {
  unsigned int u = __builtin_bit_cast(unsigned int, f);
  u += 0x7FFFu + ((u >> 16) & 1u);
  return (unsigned short)(u >> 16);
}

// --- swizzles (element index), all bijective per row, bank-spread per use ---
// 128-col u16 tile, rows 256B. For [s][c] staging + frag reads (qkv/tail).
static __device__ __forceinline__ int swzc(int r, int c) {
  int slot = ((c >> 3) ^ (r & 7) ^ ((r >> 3) & 15)) & 15;
  return r * 128 + slot * 8 + (c & 7);
}
// C-tile [o][s] u16: scalar epilogue writes + b128 row readback.
static __device__ __forceinline__ int ctix(int o, int s) {
  int slot = ((s >> 3) ^ ((o >> 1) & 7)) & 15;
  return o * 128 + slot * 8 + (s & 7);
}
// 64-col u16 tile (attn q/k/v transposed), rows 128B.
static __device__ __forceinline__ int swat(int w, int x) {
  int slot = ((x >> 3) ^ (w & 7) ^ ((w >> 3) & 7)) & 7;
  return w * 64 + slot * 8 + (x & 7);
}
// attn P/O tile [i][j] u16, rows 128B.
static __device__ __forceinline__ int pix(int i, int j) {
  int slot = ((j >> 3) ^ (((i >> 2) & 3) << 1)) & 7;
  return i * 64 + slot * 8 + (j & 7);
}
// f32 C-chunk [o<64][s<128], rows 512B (tail final output repack).
static __device__ __forceinline__ int fix32(int o, int s) {
  int slot = ((s >> 2) ^ (((o >> 2) & 3) << 2)) & 31;
  return o * 128 + slot * 4 + (s & 3);
}

// ---------------------------------------------------------------------------
// K1: fused QKV. M=128(o) x N=128(s) x K=128(c). 256 thr / 4 waves.
// ---------------------------------------------------------------------------
__global__ __launch_bounds__(256, 2) void qkv_kernel(
    const float* __restrict__ X,
    const float* __restrict__ Wq, const float* __restrict__ Bq, unsigned short* __restrict__ Yq,
    const float* __restrict__ Wk, const float* __restrict__ Bk, unsigned short* __restrict__ Yk,
    const float* __restrict__ Wv, const float* __restrict__ Bv, unsigned short* __restrict__ Yv)
{
  __shared__ unsigned short bufA[128 * 128];   // X^T[s][c], then C[o][s] repack
  __shared__ unsigned short bufB[128 * 128];   // W[o][c]
  __shared__ float bias_lds[3][128];

  const int tid  = threadIdx.x;
  const int wv   = tid >> 6;
  const int lane = tid & 63;
  const int lr   = lane & 15;
  const int lg   = lane >> 4;
  const int s0   = blockIdx.x * 128;
  const size_t xbase = (size_t)blockIdx.y * CCH * SPB;

  if (tid < 128) {
    bias_lds[0][tid] = Bq[tid];
    bias_lds[1][tid] = Bk[tid];
    bias_lds[2][tid] = Bv[tid];
  }

  // ---- stage X^T: 16 dwordx4 loads, scalar transposing ds writes ----
  {
    const int c  = tid >> 1;
    const int sh = tid & 1;
    const float* xp = X + xbase + (size_t)c * SPB + s0 + sh * 64;
#pragma unroll
    for (int p = 0; p < 16; ++p) {
      f32x4 v = *(const f32x4*)&xp[p * 4];
#pragma unroll
      for (int e = 0; e < 4; ++e)
        bufA[swzc(sh * 64 + p * 4 + e, c)] = f2b(v[e]);
    }
  }
  __syncthreads();

  // ---- read B-fragments once; reused by all three convs ----
  u16x8 bfr[2][4];
#pragma unroll
  for (int nf = 0; nf < 2; ++nf)
#pragma unroll
    for (int ks = 0; ks < 4; ++ks)
      bfr[nf][ks] = *(const u16x8*)&bufA[swzc(wv * 32 + nf * 16 + lr, ks * 32 + lg * 8)];

  auto do_conv = [&](const float* __restrict__ W, int ci,
                     unsigned short* __restrict__ Y) {
    // stage W (f32 -> bf16), b128 ds writes
    {
      const int m  = tid >> 1;
      const int hh = (tid & 1) * 64;
#pragma unroll
      for (int p = 0; p < 8; ++p) {
        const int c0 = hh + p * 8;
        f32x4 a = *(const f32x4*)&W[m * 128 + c0];
        f32x4 b = *(const f32x4*)&W[m * 128 + c0 + 4];
        u16x8 u;
#pragma unroll
        for (int i = 0; i < 4; ++i) { u[i] = f2b(a[i]); u[4 + i] = f2b(b[i]); }
        *(u16x8*)&bufB[swzc(m, c0)] = u;
      }
    }
    __syncthreads();

    f32x4 acc[8][2];
#pragma unroll
    for (int mf = 0; mf < 8; ++mf)
#pragma unroll
      for (int nf = 0; nf < 2; ++nf) {
        f32x4 z = {0.f, 0.f, 0.f, 0.f};
        acc[mf][nf] = z;
      }
#pragma unroll
    for (int ks = 0; ks < 4; ++ks) {
      const int k0 = ks * 32 + lg * 8;
#pragma unroll
      for (int mf = 0; mf < 8; ++mf) {
        u16x8 afr = *(const u16x8*)&bufB[swzc(mf * 16 + lr, k0)];
        acc[mf][0] = MFMA16(afr, bfr[0][ks], acc[mf][0]);
        acc[mf][1] = MFMA16(afr, bfr[1][ks], acc[mf][1]);
      }
    }

    // epilogue: scalar repack into bufA as C[o][s_local]
#pragma unroll
    for (int mf = 0; mf < 8; ++mf)
#pragma unroll
      for (int nf = 0; nf < 2; ++nf)
#pragma unroll
        for (int r = 0; r < 4; ++r) {
          const int o  = mf * 16 + lg * 4 + r;
          const int sl = wv * 32 + nf * 16 + lr;
          bufA[ctix(o, sl)] = f2b(acc[mf][nf][r] + bias_lds[ci][o]);
        }
    __syncthreads();

    // vectorized readback + 16B global stores
    {
      const int o  = tid >> 1;
      const int sh = tid & 1;
#pragma unroll
      for (int i = 0; i < 8; ++i) {
        const int j = sh * 8 + i;
        u16x8 v = *(const u16x8*)&bufA[ctix(o, j * 8)];
        *(u16x8*)&Y[xbase + (size_t)o * SPB + s0 + j * 8] = v;
      }
    }
  };

  do_conv(Wq, 0, Yq);
  do_conv(Wk, 1, Yk);
  do_conv(Wv, 2, Yv);
}

// ---------------------------------------------------------------------------
// K2: attention per (b,c,d) 64x64 slice. 1 WG / slice, wave wv owns 16 rows.
// ---------------------------------------------------------------------------
__global__ __launch_bounds__(256, 4) void attn64_kernel(
    const unsigned short* __restrict__ Q,
    const unsigned short* __restrict__ K,
    const unsigned short* __restrict__ V,
    unsigned short* __restrict__ O)
{
  __shared__ unsigned short qt[4096];   // Q^T[w][x]
  __shared__ unsigned short kt[4096];   // K^T[w][x]
  __shared__ unsigned short vt[4096];   // V^T[w][x]
  __shared__ unsigned short pbuf[4096]; // P rows, then O rows (wave-private)

  const int tid  = threadIdx.x;
  const int wv   = tid >> 6;
  const int lane = tid & 63;
  const int lr   = lane & 15;
  const int lg   = lane >> 4;
  const size_t base = (size_t)blockIdx.x * 4096;

  // ---- stage transposed: 2 b128 loads/tensor + scalar ds writes ----
  {
    const int x  = tid >> 2;
    const int g4 = (tid & 3) * 16;
#pragma unroll
    for (int h = 0; h < 2; ++h) {
      const size_t g = base + (size_t)x * 64 + g4 + h * 8;
      u16x8 qv = *(const u16x8*)&Q[g];
      u16x8 kv = *(const u16x8*)&K[g];
      u16x8 vv = *(const u16x8*)&V[g];
#pragma unroll
      for (int e = 0; e < 8; ++e) {
        const int w = g4 + h * 8 + e;
        qt[swat(w, x)] = qv[e];
        kt[swat(w, x)] = kv[e];
        vt[swat(w, x)] = vv[e];
      }
    }
  }
  __syncthreads();

  // ---- S = Q^T K ----
  f32x4 sacc[4];
#pragma unroll
  for (int nf = 0; nf < 4; ++nf) { f32x4 z = {0.f, 0.f, 0.f, 0.f}; sacc[nf] = z; }
#pragma unroll
  for (int ks = 0; ks < 2; ++ks) {
    const int k0 = ks * 32 + lg * 8;
    u16x8 a = *(const u16x8*)&qt[swat(wv * 16 + lr, k0)];
#pragma unroll
    for (int nf = 0; nf < 4; ++nf) {
      u16x8 bb = *(const u16x8*)&kt[swat(nf * 16 + lr, k0)];
      sacc[nf] = MFMA16(a, bb, sacc[nf]);
    }
  }

  // ---- softmax over j; P -> pbuf (wave-private rows) ----
#pragma unroll
  for (int r = 0; r < 4; ++r) {
    float m = fmaxf(fmaxf(sacc[0][r], sacc[1][r]), fmaxf(sacc[2][r], sacc[3][r]));
    m = fmaxf(m, __shfl_xor(m, 1));
    m = fmaxf(m, __shfl_xor(m, 2));
    m = fmaxf(m, __shfl_xor(m, 4));
    m = fmaxf(m, __shfl_xor(m, 8));
    float sum = 0.f;
#pragma unroll
    for (int nf = 0; nf < 4; ++nf) {
      float p = __expf(sacc[nf][r] - m);
      sacc[nf][r] = p;
      sum += p;
    }
    sum += __shfl_xor(sum, 1);
    sum += __shfl_xor(sum, 2);
    sum += __shfl_xor(sum, 4);
    sum += __shfl_xor(sum, 8);
    const float inv = 1.f / sum;
    const int i = wv * 16 + lg * 4 + r;
#pragma unroll
    for (int nf = 0; nf < 4; ++nf)
      pbuf[pix(i, nf * 16 + lr)] = f2b(sacc[nf][r] * inv);
  }

  // ---- O = P V ----
  f32x4 oacc[4];
#pragma unroll
  for (int nf = 0; nf < 4; ++nf) { f32x4 z = {0.f, 0.f, 0.f, 0.f}; oacc[nf] = z; }
#pragma unroll
  for (int ks = 0; ks < 2; ++ks) {
    const int k0 = ks * 32 + lg * 8;
    u16x8 a = *(const u16x8*)&pbuf[pix(wv * 16 + lr, k0)];
#pragma unroll
    for (int nf = 0; nf < 4; ++nf) {
      u16x8 bb = *(const u16x8*)&vt[swat(nf * 16 + lr, k0)];
      oacc[nf] = MFMA16(a, bb, oacc[nf]);
    }
  }

  // ---- O epilogue into pbuf (overwrites own wave's P rows) ----
#pragma unroll
  for (int nf = 0; nf < 4; ++nf)
#pragma unroll
    for (int r = 0; r < 4; ++r) {
      const int i = wv * 16 + lg * 4 + r;
      pbuf[pix(i, nf * 16 + lr)] = f2b(oacc[nf][r]);
    }
  __syncthreads();

  // ---- vectorized O readback + stores ----
  {
    const int i  = tid >> 2;
    const int g4 = (tid & 3) * 16;
#pragma unroll
    for (int h = 0; h < 2; ++h) {
      u16x8 v = *(const u16x8*)&pbuf[pix(i, g4 + h * 8)];
      *(u16x8*)&O[base + (size_t)i * 64 + g4 + h * 8] = v;
    }
  }
}

// ---------------------------------------------------------------------------
// K3: tail a1+relu -> a2 -> f. In-LDS chaining on wave-private rows; final
// f32 output repacked through LDS in two 32KB chunks -> dwordx4 stores.
// ---------------------------------------------------------------------------
__global__ __launch_bounds__(256, 2) void tail_kernel(
    const unsigned short* __restrict__ Xb,
    const float* __restrict__ W1, const float* __restrict__ B1,
    const float* __restrict__ W2, const float* __restrict__ B2,
    const float* __restrict__ W3, const float* __restrict__ B3,
    float* __restrict__ OUT)
{
  __shared__ unsigned short bufA[128 * 128];   // X^T chain, then f32 C chunks
  __shared__ unsigned short bufB[128 * 128];   // W
  __shared__ float bias_lds[3][128];
  float* fA = (float*)bufA;                    // [64][128] f32 view

  const int tid  = threadIdx.x;
  const int wv   = tid >> 6;
  const int lane = tid & 63;
  const int lr   = lane & 15;
  const int lg   = lane >> 4;
  const int s0   = blockIdx.x * 128;
  const size_t xbase = (size_t)blockIdx.y * CCH * SPB;

  if (tid < 128) {
    bias_lds[0][tid] = B1[tid];
    bias_lds[1][tid] = B2[tid];
    bias_lds[2][tid] = B3[tid];
  }

  // ---- stage X^T (bf16): 8 b128 loads + scalar transposing ds writes ----
  {
    const int c  = tid >> 1;
    const int sh = tid & 1;
    const unsigned short* xp = Xb + xbase + (size_t)c * SPB + s0 + sh * 64;
#pragma unroll
    for (int i = 0; i < 8; ++i) {
      u16x8 v = *(const u16x8*)&xp[i * 8];
#pragma unroll
      for (int e = 0; e < 8; ++e)
        bufA[swzc(sh * 64 + i * 8 + e, c)] = v[e];
    }
  }
  __syncthreads();

  u16x8 bfr[2][4];
#pragma unroll
  for (int nf = 0; nf < 2; ++nf)
#pragma unroll
    for (int ks = 0; ks < 4; ++ks)
      bfr[nf][ks] = *(const u16x8*)&bufA[swzc(wv * 32 + nf * 16 + lr, ks * 32 + lg * 8)];

  auto stage_w = [&](const float* __restrict__ W) {
    const int m  = tid >> 1;
    const int hh = (tid & 1) * 64;
#pragma unroll
    for (int p = 0; p < 8; ++p) {
      const int c0 = hh + p * 8;
      f32x4 a = *(const f32x4*)&W[m * 128 + c0];
      f32x4 b = *(const f32x4*)&W[m * 128 + c0 + 4];
      u16x8 u;
#pragma unroll
      for (int i = 0; i < 4; ++i) { u[i] = f2b(a[i]); u[4 + i] = f2b(b[i]); }
      *(u16x8*)&bufB[swzc(m, c0)] = u;
    }
  };

  f32x4 acc[8][2];
  auto gemm = [&]() {
#pragma unroll
    for (int mf = 0; mf < 8; ++mf)
#pragma unroll
      for (int nf = 0; nf < 2; ++nf) {
        f32x4 z = {0.f, 0.f, 0.f, 0.f};
        acc[mf][nf] = z;
      }
#pragma unroll
    for (int ks = 0; ks < 4; ++ks) {
      const int k0 = ks * 32 + lg * 8;
#pragma unroll
      for (int mf = 0; mf < 8; ++mf) {
        u16x8 afr = *(const u16x8*)&bufB[swzc(mf * 16 + lr, k0)];
        acc[mf][0] = MFMA16(afr, bfr[0][ks], acc[mf][0]);
        acc[mf][1] = MFMA16(afr, bfr[1][ks], acc[mf][1]);
      }
    }
  };

  // epilogue -> bufA[s][o] (wave-private rows), then refresh frags
  auto epi_chain = [&](int ci, bool relu) {
#pragma unroll
    for (int mf = 0; mf < 8; ++mf)
#pragma unroll
      for (int nf = 0; nf < 2; ++nf)
#pragma unroll
        for (int r = 0; r < 4; ++r) {
          const int o  = mf * 16 + lg * 4 + r;
          const int sl = wv * 32 + nf * 16 + lr;
          float val = acc[mf][nf][r] + bias_lds[ci][o];
          if (relu) val = fmaxf(val, 0.f);
          bufA[swzc(sl, o)] = f2b(val);
        }
#pragma unroll
    for (int nf = 0; nf < 2; ++nf)
#pragma unroll
      for (int ks = 0; ks < 4; ++ks)
        bfr[nf][ks] = *(const u16x8*)&bufA[swzc(wv * 32 + nf * 16 + lr, ks * 32 + lg * 8)];
  };

  stage_w(W1);
  __syncthreads();
  gemm();
  epi_chain(0, true);
  __syncthreads();

  stage_w(W2);
  __syncthreads();
  gemm();
  epi_chain(1, false);
  __syncthreads();

  stage_w(W3);
  __syncthreads();
  gemm();

  // ---- final f32 output via two 32KB LDS chunks ----
#pragma unroll
  for (int half = 0; half < 2; ++half) {
#pragma unroll
    for (int mf = half * 4; mf < half * 4 + 4; ++mf)
#pragma unroll
      for (int nf = 0; nf < 2; ++nf)
#pragma unroll
        for (int r = 0; r < 4; ++r) {
          const int o  = mf * 16 + lg * 4 + r;
          const int sl = wv * 32 + nf * 16 + lr;
          fA[fix32(o - half * 64, sl)] = acc[mf][nf][r] + bias_lds[2][o];
        }
    __syncthreads();
    {
      const int o6 = tid >> 2;
      const int q  = tid & 3;
#pragma unroll
      for (int i = 0; i < 8; ++i) {
        f32x4 v = *(const f32x4*)&fA[fix32(o6, q * 32 + i * 4)];
        *(f32x4*)&OUT[xbase + (size_t)(o6 + half * 64) * SPB + s0 + q * 32 + i * 4] = v;
      }
    }
    __syncthreads();
  }
}

extern "C" void kernel_launch(void* const* d_in, const int* in_sizes, int n_in,
                              void* d_out, int out_size, void* d_ws, size_t ws_size,
                              hipStream_t stream) {
  const float* x   = (const float*)d_in[0];
  const float* Wq  = (const float*)d_in[1];  const float* bq  = (const float*)d_in[2];
  const float* Wk  = (const float*)d_in[3];  const float* bk  = (const float*)d_in[4];
  const float* Wv  = (const float*)d_in[5];  const float* bv  = (const float*)d_in[6];
  const float* Wa1 = (const float*)d_in[7];  const float* ba1 = (const float*)d_in[8];
  const float* Wa2 = (const float*)d_in[9];  const float* ba2 = (const float*)d_in[10];
  const float* Wf  = (const float*)d_in[11]; const float* bf_ = (const float*)d_in[12];

  // bf16 scratch: q in ws; k,v packed into d_out (dead before final f32 write).
  unsigned short* qb = (unsigned short*)d_ws;
  unsigned short* kb = (unsigned short*)d_out;
  unsigned short* vb = kb + (size_t)NBATCH * CCH * SPB;

  dim3 grid(SPB / 128, NBATCH);

  qkv_kernel<<<grid, 256, 0, stream>>>(x, Wq, bq, qb, Wk, bk, kb, Wv, bv, vb);

  attn64_kernel<<<NBATCH * CCH * 16, 256, 0, stream>>>(qb, kb, vb, qb);

  tail_kernel<<<grid, 256, 0, stream>>>(qb, Wa1, ba1, Wa2, ba2, Wf, bf_,
                                        (float*)d_out);
}

// Round 5
// 235.048 us; speedup vs baseline: 1.3506x; 1.2308x over previous
//
#include <hip/hip_runtime.h>

// SelfAttention3d: B=4, C=128, D=16, H=W=64.
//   K0 prep  : Wq,Wk,Wv,Wa1,Wa2,Wf f32 -> bf16, pre-swizzled (LDS layout), in ws
//   K1 qkv   : q -> ws, k -> d_out[0:67M], v -> d_out[67M:134M]   (bf16)
//              W staged via global_load_lds(16B) from pre-swizzled tables
//   K2 attn  : per (b,c,d) 64x64 slice, O -> ws (in-place over q)
//   K3 tail  : a1+relu -> a2 -> f chained in LDS, f32 -> d_out

#define CCH 128
#define SPB 65536      // per-batch spatial = D*H*W
#define NBATCH 4
#define WTAB 16384     // elements per 128x128 weight table

typedef float f32x4 __attribute__((ext_vector_type(4)));
typedef __bf16 bf16x8 __attribute__((ext_vector_type(8)));
typedef short s16x8 __attribute__((ext_vector_type(8)));
typedef unsigned short u16x8 __attribute__((ext_vector_type(8)));
typedef unsigned short u16x4 __attribute__((ext_vector_type(4)));

// ---- MFMA wrapper: robust to builtin signature (v8i16 vs v8bf16) ----
template <typename T>
static __device__ __forceinline__ auto mfma_try(T a, T b, f32x4 c, int)
    -> decltype(__builtin_amdgcn_mfma_f32_16x16x32_bf16(a, b, c, 0, 0, 0)) {
  return __builtin_amdgcn_mfma_f32_16x16x32_bf16(a, b, c, 0, 0, 0);
}
template <typename T>
static __device__ __forceinline__ f32x4 mfma_try(T a, T b, f32x4 c, long) {
  return __builtin_amdgcn_mfma_f32_16x16x32_bf16(
      __builtin_bit_cast(bf16x8, a), __builtin_bit_cast(bf16x8, b), c, 0, 0, 0);
}
static __device__ __forceinline__ f32x4 MFMA16(u16x8 a, u16x8 b, f32x4 c) {
  return mfma_try(__builtin_bit_cast(s16x8, a), __builtin_bit_cast(s16x8, b), c, 0);
}

// f32 -> bf16 bits via compiler cast (RNE; emits v_cvt_pk_bf16_f32 pairs)
static __device__ __forceinline__ unsigned short f2b(float f) {
  return __builtin_bit_cast(unsigned short, (__bf16)f);
}

// async global->LDS, 16B per lane. Dest must be linear per-lane (base+lane*16).
static __device__ __forceinline__ void glds16(const unsigned short* g,
                                              unsigned short* l) {
  __builtin_amdgcn_global_load_lds(
      (const __attribute__((address_space(1))) unsigned int*)g,
      (__attribute__((address_space(3))) unsigned int*)l, 16, 0, 0);
}

// --- swizzles (element index), all bijective per row ---
// 128-col u16 tile, rows 256B: staging + MFMA frag reads (qkv/tail, W tables).
static __device__ __forceinline__ int swzc(int r, int c) {
  int slot = ((c >> 3) ^ (r & 7) ^ ((r >> 3) & 15)) & 15;
  return r * 128 + slot * 8 + (c & 7);
}
// C-tile [o][s] u16: scalar epilogue writes + b128 row readback.
static __device__ __forceinline__ int ctix(int o, int s) {
  int slot = ((s >> 3) ^ ((o >> 1) & 7)) & 15;
  return o * 128 + slot * 8 + (s & 7);
}
// 64-col u16 tile (attn q/k/v transposed), rows 128B.
static __device__ __forceinline__ int swat(int w, int x) {
  int slot = ((x >> 3) ^ (w & 7) ^ ((w >> 3) & 7)) & 7;
  return w * 64 + slot * 8 + (x & 7);
}
// attn P/O tile [i][j] u16, rows 128B.
static __device__ __forceinline__ int pix(int i, int j) {
  int slot = ((j >> 3) ^ (((i >> 2) & 3) << 1)) & 7;
  return i * 64 + slot * 8 + (j & 7);
}
// f32 C-chunk [o<64][s<128], rows 512B (tail final output repack).
static __device__ __forceinline__ int fix32(int o, int s) {
  int slot = ((s >> 2) ^ (((o >> 2) & 3) << 2)) & 31;
  return o * 128 + slot * 4 + (s & 3);
}

// ---------------------------------------------------------------------------
// K0: one-time weight conversion f32 -> bf16 into swizzled LDS-image tables.
// 6 WGs x 256 threads; thread converts 64 elements (16 x f32x4).
// ---------------------------------------------------------------------------
__global__ __launch_bounds__(256) void prep_w_kernel(
    const float* __restrict__ Wq, const float* __restrict__ Wk,
    const float* __restrict__ Wv, const float* __restrict__ W1,
    const float* __restrict__ W2, const float* __restrict__ W3,
    unsigned short* __restrict__ out)
{
  const float* Ws[6] = {Wq, Wk, Wv, W1, W2, W3};
  const float* W = Ws[blockIdx.x];
  unsigned short* o = out + (size_t)blockIdx.x * WTAB;
  const int tid = threadIdx.x;
#pragma unroll
  for (int p = 0; p < 16; ++p) {
    const int base = p * 1024 + tid * 4;       // 4-aligned within a 128-row
    const int m = base >> 7;
    const int c0 = base & 127;
    f32x4 v = *(const f32x4*)&W[base];
    u16x4 u;
#pragma unroll
    for (int e = 0; e < 4; ++e) u[e] = f2b(v[e]);
    *(u16x4*)&o[swzc(m, c0)] = u;              // c0..c0+3 share one 8-slot
  }
}

// ---------------------------------------------------------------------------
// K1: fused QKV. M=128(o) x N=128(s) x K=128(c). 256 thr / 4 waves.
// ---------------------------------------------------------------------------
__global__ __launch_bounds__(256, 2) void qkv_kernel(
    const float* __restrict__ X, const unsigned short* __restrict__ Wbf,
    const float* __restrict__ Bq, const float* __restrict__ Bk,
    const float* __restrict__ Bv,
    unsigned short* __restrict__ Yq, unsigned short* __restrict__ Yk,
    unsigned short* __restrict__ Yv)
{
  __shared__ unsigned short wl[WTAB];          // W (swizzled image via glds)
  __shared__ unsigned short xc[WTAB];          // X^T[s][c], then C[o][s] repack
  __shared__ float bias_lds[3][128];

  const int tid  = threadIdx.x;
  const int wv   = tid >> 6;
  const int lane = tid & 63;
  const int lr   = lane & 15;
  const int lg   = lane >> 4;
  const int s0   = blockIdx.x * 128;
  const size_t xbase = (size_t)blockIdx.y * CCH * SPB;
  const int gofs = (tid >> 6) * 512 + (tid & 63) * 8;   // glds per-lane offset

  // ---- issue Wq load early (completes under the X staging) ----
#pragma unroll
  for (int p = 0; p < 8; ++p)
    glds16(&Wbf[p * 2048 + gofs], &wl[p * 2048 + gofs]);

  if (tid < 128) {
    bias_lds[0][tid] = Bq[tid];
    bias_lds[1][tid] = Bk[tid];
    bias_lds[2][tid] = Bv[tid];
  }

  // ---- stage X^T: 16 dwordx4 loads, cvt, scalar transposing ds writes ----
  {
    const int c  = tid >> 1;
    const int sh = tid & 1;
    const float* xp = X + xbase + (size_t)c * SPB + s0 + sh * 64;
#pragma unroll
    for (int p = 0; p < 16; ++p) {
      f32x4 v = *(const f32x4*)&xp[p * 4];
#pragma unroll
      for (int e = 0; e < 4; ++e)
        xc[swzc(sh * 64 + p * 4 + e, c)] = f2b(v[e]);
    }
  }
  __syncthreads();   // S1: X^T staged, Wq resident (vmcnt drained)

  // ---- read B-fragments once; reused by all three convs ----
  u16x8 bfr[2][4];
#pragma unroll
  for (int nf = 0; nf < 2; ++nf)
#pragma unroll
    for (int ks = 0; ks < 4; ++ks)
      bfr[nf][ks] = *(const u16x8*)&xc[swzc(wv * 32 + nf * 16 + lr, ks * 32 + lg * 8)];
  __syncthreads();   // S2: all waves read bfr; xc free for C repack

#pragma unroll
  for (int ci = 0; ci < 3; ++ci) {
    unsigned short* Y = (ci == 0) ? Yq : (ci == 1) ? Yk : Yv;

    // ---- GEMM (wl holds W_ci) ----
    f32x4 acc[8][2];
#pragma unroll
    for (int mf = 0; mf < 8; ++mf)
#pragma unroll
      for (int nf = 0; nf < 2; ++nf) {
        f32x4 z = {0.f, 0.f, 0.f, 0.f};
        acc[mf][nf] = z;
      }
#pragma unroll
    for (int ks = 0; ks < 4; ++ks) {
      const int k0 = ks * 32 + lg * 8;
#pragma unroll
      for (int mf = 0; mf < 8; ++mf) {
        u16x8 afr = *(const u16x8*)&wl[swzc(mf * 16 + lr, k0)];
        acc[mf][0] = MFMA16(afr, bfr[0][ks], acc[mf][0]);
        acc[mf][1] = MFMA16(afr, bfr[1][ks], acc[mf][1]);
      }
    }
    __syncthreads();   // S3: all wl reads done

    // ---- prefetch next W into wl (async, waits at S5) ----
    if (ci < 2) {
      const unsigned short* Wn = Wbf + (size_t)(ci + 1) * WTAB;
#pragma unroll
      for (int p = 0; p < 8; ++p)
        glds16(&Wn[p * 2048 + gofs], &wl[p * 2048 + gofs]);
    }

    // ---- epilogue: bias + cvt, scalar repack into xc as C[o][s] ----
#pragma unroll
    for (int mf = 0; mf < 8; ++mf)
#pragma unroll
      for (int nf = 0; nf < 2; ++nf)
#pragma unroll
        for (int r = 0; r < 4; ++r) {
          const int o  = mf * 16 + lg * 4 + r;
          const int sl = wv * 32 + nf * 16 + lr;
          xc[ctix(o, sl)] = f2b(acc[mf][nf][r] + bias_lds[ci][o]);
        }
    __syncthreads();   // S4: repack visible

    // ---- vectorized readback + 16B global stores ----
    {
      const int o  = tid >> 1;
      const int sh = tid & 1;
#pragma unroll
      for (int i = 0; i < 8; ++i) {
        const int j = sh * 8 + i;
        u16x8 v = *(const u16x8*)&xc[ctix(o, j * 8)];
        *(u16x8*)&Y[xbase + (size_t)o * SPB + s0 + j * 8] = v;
      }
    }
    if (ci < 2) __syncthreads();   // S5: xc free; W_{ci+1} resident
  }
}

// ---------------------------------------------------------------------------
// K2: attention per (b,c,d) 64x64 slice. 1 WG / slice, wave wv owns 16 rows.
// (unchanged from round 4)
// ---------------------------------------------------------------------------
__global__ __launch_bounds__(256, 4) void attn64_kernel(
    const unsigned short* __restrict__ Q,
    const unsigned short* __restrict__ K,
    const unsigned short* __restrict__ V,
    unsigned short* __restrict__ O)
{
  __shared__ unsigned short qt[4096];   // Q^T[w][x]
  __shared__ unsigned short kt[4096];   // K^T[w][x]
  __shared__ unsigned short vt[4096];   // V^T[w][x]
  __shared__ unsigned short pbuf[4096]; // P rows, then O rows

  const int tid  = threadIdx.x;
  const int wv   = tid >> 6;
  const int lane = tid & 63;
  const int lr   = lane & 15;
  const int lg   = lane >> 4;
  const size_t base = (size_t)blockIdx.x * 4096;

  {
    const int x  = tid >> 2;
    const int g4 = (tid & 3) * 16;
#pragma unroll
    for (int h = 0; h < 2; ++h) {
      const size_t g = base + (size_t)x * 64 + g4 + h * 8;
      u16x8 qv = *(const u16x8*)&Q[g];
      u16x8 kv = *(const u16x8*)&K[g];
      u16x8 vv = *(const u16x8*)&V[g];
#pragma unroll
      for (int e = 0; e < 8; ++e) {
        const int w = g4 + h * 8 + e;
        qt[swat(w, x)] = qv[e];
        kt[swat(w, x)] = kv[e];
        vt[swat(w, x)] = vv[e];
      }
    }
  }
  __syncthreads();

  f32x4 sacc[4];
#pragma unroll
  for (int nf = 0; nf < 4; ++nf) { f32x4 z = {0.f, 0.f, 0.f, 0.f}; sacc[nf] = z; }
#pragma unroll
  for (int ks = 0; ks < 2; ++ks) {
    const int k0 = ks * 32 + lg * 8;
    u16x8 a = *(const u16x8*)&qt[swat(wv * 16 + lr, k0)];
#pragma unroll
    for (int nf = 0; nf < 4; ++nf) {
      u16x8 bb = *(const u16x8*)&kt[swat(nf * 16 + lr, k0)];
      sacc[nf] = MFMA16(a, bb, sacc[nf]);
    }
  }

#pragma unroll
  for (int r = 0; r < 4; ++r) {
    float m = fmaxf(fmaxf(sacc[0][r], sacc[1][r]), fmaxf(sacc[2][r], sacc[3][r]));
    m = fmaxf(m, __shfl_xor(m, 1));
    m = fmaxf(m, __shfl_xor(m, 2));
    m = fmaxf(m, __shfl_xor(m, 4));
    m = fmaxf(m, __shfl_xor(m, 8));
    float sum = 0.f;
#pragma unroll
    for (int nf = 0; nf < 4; ++nf) {
      float p = __expf(sacc[nf][r] - m);
      sacc[nf][r] = p;
      sum += p;
    }
    sum += __shfl_xor(sum, 1);
    sum += __shfl_xor(sum, 2);
    sum += __shfl_xor(sum, 4);
    sum += __shfl_xor(sum, 8);
    const float inv = 1.f / sum;
    const int i = wv * 16 + lg * 4 + r;
#pragma unroll
    for (int nf = 0; nf < 4; ++nf)
      pbuf[pix(i, nf * 16 + lr)] = f2b(sacc[nf][r] * inv);
  }

  f32x4 oacc[4];
#pragma unroll
  for (int nf = 0; nf < 4; ++nf) { f32x4 z = {0.f, 0.f, 0.f, 0.f}; oacc[nf] = z; }
#pragma unroll
  for (int ks = 0; ks < 2; ++ks) {
    const int k0 = ks * 32 + lg * 8;
    u16x8 a = *(const u16x8*)&pbuf[pix(wv * 16 + lr, k0)];
#pragma unroll
    for (int nf = 0; nf < 4; ++nf) {
      u16x8 bb = *(const u16x8*)&vt[swat(nf * 16 + lr, k0)];
      oacc[nf] = MFMA16(a, bb, oacc[nf]);
    }
  }

#pragma unroll
  for (int nf = 0; nf < 4; ++nf)
#pragma unroll
    for (int r = 0; r < 4; ++r) {
      const int i = wv * 16 + lg * 4 + r;
      pbuf[pix(i, nf * 16 + lr)] = f2b(oacc[nf][r]);
    }
  __syncthreads();

  {
    const int i  = tid >> 2;
    const int g4 = (tid & 3) * 16;
#pragma unroll
    for (int h = 0; h < 2; ++h) {
      u16x8 v = *(const u16x8*)&pbuf[pix(i, g4 + h * 8)];
      *(u16x8*)&O[base + (size_t)i * 64 + g4 + h * 8] = v;
    }
  }
}

// ---------------------------------------------------------------------------
// K3: tail a1+relu -> a2 -> f. In-LDS chaining on wave-private rows; W via
// glds from pre-swizzled tables; final f32 repacked in two 32KB chunks.
// ---------------------------------------------------------------------------
__global__ __launch_bounds__(256, 2) void tail_kernel(
    const unsigned short* __restrict__ Xb, const unsigned short* __restrict__ Wbf,
    const float* __restrict__ B1, const float* __restrict__ B2,
    const float* __restrict__ B3, float* __restrict__ OUT)
{
  __shared__ unsigned short wl[WTAB];
  __shared__ unsigned short xc[WTAB];
  __shared__ float bias_lds[3][128];
  float* fA = (float*)xc;                      // [64][128] f32 view

  const int tid  = threadIdx.x;
  const int wv   = tid >> 6;
  const int lane = tid & 63;
  const int lr   = lane & 15;
  const int lg   = lane >> 4;
  const int s0   = blockIdx.x * 128;
  const size_t xbase = (size_t)blockIdx.y * CCH * SPB;
  const int gofs = (tid >> 6) * 512 + (tid & 63) * 8;

  // issue W1 early
#pragma unroll
  for (int p = 0; p < 8; ++p)
    glds16(&Wbf[p * 2048 + gofs], &wl[p * 2048 + gofs]);

  if (tid < 128) {
    bias_lds[0][tid] = B1[tid];
    bias_lds[1][tid] = B2[tid];
    bias_lds[2][tid] = B3[tid];
  }

  // ---- stage X^T (bf16): 8 b128 loads + scalar transposing ds writes ----
  {
    const int c  = tid >> 1;
    const int sh = tid & 1;
    const unsigned short* xp = Xb + xbase + (size_t)c * SPB + s0 + sh * 64;
#pragma unroll
    for (int i = 0; i < 8; ++i) {
      u16x8 v = *(const u16x8*)&xp[i * 8];
#pragma unroll
      for (int e = 0; e < 8; ++e)
        xc[swzc(sh * 64 + i * 8 + e, c)] = v[e];
    }
  }
  __syncthreads();   // S1: X^T + W1 ready

  u16x8 bfr[2][4];
#pragma unroll
  for (int nf = 0; nf < 2; ++nf)
#pragma unroll
    for (int ks = 0; ks < 4; ++ks)
      bfr[nf][ks] = *(const u16x8*)&xc[swzc(wv * 32 + nf * 16 + lr, ks * 32 + lg * 8)];

  f32x4 acc[8][2];
  auto gemm = [&]() {
#pragma unroll
    for (int mf = 0; mf < 8; ++mf)
#pragma unroll
      for (int nf = 0; nf < 2; ++nf) {
        f32x4 z = {0.f, 0.f, 0.f, 0.f};
        acc[mf][nf] = z;
      }
#pragma unroll
    for (int ks = 0; ks < 4; ++ks) {
      const int k0 = ks * 32 + lg * 8;
#pragma unroll
      for (int mf = 0; mf < 8; ++mf) {
        u16x8 afr = *(const u16x8*)&wl[swzc(mf * 16 + lr, k0)];
        acc[mf][0] = MFMA16(afr, bfr[0][ks], acc[mf][0]);
        acc[mf][1] = MFMA16(afr, bfr[1][ks], acc[mf][1]);
      }
    }
  };

  // chain epilogue: wave-private rows of xc; no barrier needed around it
  auto epi_chain = [&](int ci, bool relu) {
#pragma unroll
    for (int mf = 0; mf < 8; ++mf)
#pragma unroll
      for (int nf = 0; nf < 2; ++nf)
#pragma unroll
        for (int r = 0; r < 4; ++r) {
          const int o  = mf * 16 + lg * 4 + r;
          const int sl = wv * 32 + nf * 16 + lr;
          float val = acc[mf][nf][r] + bias_lds[ci][o];
          if (relu) val = fmaxf(val, 0.f);
          xc[swzc(sl, o)] = f2b(val);
        }
#pragma unroll
    for (int nf = 0; nf < 2; ++nf)
#pragma unroll
      for (int ks = 0; ks < 4; ++ks)
        bfr[nf][ks] = *(const u16x8*)&xc[swzc(wv * 32 + nf * 16 + lr, ks * 32 + lg * 8)];
  };

#pragma unroll
  for (int j = 0; j < 2; ++j) {
    gemm();
    __syncthreads();   // S2: wl reads done by all waves
    const unsigned short* Wn = Wbf + (size_t)(j + 1) * WTAB;
#pragma unroll
    for (int p = 0; p < 8; ++p)
      glds16(&Wn[p * 2048 + gofs], &wl[p * 2048 + gofs]);
    epi_chain(j, j == 0);
    __syncthreads();   // S3: next W resident (vmcnt drained); xc now dead
  }
  gemm();              // W3

  // ---- final f32 output via two 32KB LDS chunks ----
#pragma unroll
  for (int half = 0; half < 2; ++half) {
#pragma unroll
    for (int mf = half * 4; mf < half * 4 + 4; ++mf)
#pragma unroll
      for (int nf = 0; nf < 2; ++nf)
#pragma unroll
        for (int r = 0; r < 4; ++r) {
          const int o  = mf * 16 + lg * 4 + r;
          const int sl = wv * 32 + nf * 16 + lr;
          fA[fix32(o - half * 64, sl)] = acc[mf][nf][r] + bias_lds[2][o];
        }
    __syncthreads();
    {
      const int o6 = tid >> 2;
      const int q  = tid & 3;
#pragma unroll
      for (int i = 0; i < 8; ++i) {
        f32x4 v = *(const f32x4*)&fA[fix32(o6, q * 32 + i * 4)];
        *(f32x4*)&OUT[xbase + (size_t)(o6 + half * 64) * SPB + s0 + q * 32 + i * 4] = v;
      }
    }
    if (half == 0) __syncthreads();
  }
}

extern "C" void kernel_launch(void* const* d_in, const int* in_sizes, int n_in,
                              void* d_out, int out_size, void* d_ws, size_t ws_size,
                              hipStream_t stream) {
  const float* x   = (const float*)d_in[0];
  const float* Wq  = (const float*)d_in[1];  const float* bq  = (const float*)d_in[2];
  const float* Wk  = (const float*)d_in[3];  const float* bk  = (const float*)d_in[4];
  const float* Wv  = (const float*)d_in[5];  const float* bv  = (const float*)d_in[6];
  const float* Wa1 = (const float*)d_in[7];  const float* ba1 = (const float*)d_in[8];
  const float* Wa2 = (const float*)d_in[9];  const float* ba2 = (const float*)d_in[10];
  const float* Wf  = (const float*)d_in[11]; const float* bf_ = (const float*)d_in[12];

  // ws layout: q (67.1MB) then 6 bf16 weight tables (192KB).
  unsigned short* qb  = (unsigned short*)d_ws;
  unsigned short* wbf = qb + (size_t)NBATCH * CCH * SPB;
  // k,v packed into d_out (dead before final f32 write).
  unsigned short* kb = (unsigned short*)d_out;
  unsigned short* vb = kb + (size_t)NBATCH * CCH * SPB;

  dim3 grid(SPB / 128, NBATCH);

  prep_w_kernel<<<6, 256, 0, stream>>>(Wq, Wk, Wv, Wa1, Wa2, Wf, wbf);

  qkv_kernel<<<grid, 256, 0, stream>>>(x, wbf, bq, bk, bv, qb, kb, vb);

  attn64_kernel<<<NBATCH * CCH * 16, 256, 0, stream>>>(qb, kb, vb, qb);

  tail_kernel<<<grid, 256, 0, stream>>>(qb, wbf + (size_t)3 * WTAB,
                                        ba1, ba2, bf_, (float*)d_out);
}

// Round 6
// 218.973 us; speedup vs baseline: 1.4497x; 1.0734x over previous
//
#include <hip/hip_runtime.h>

// SelfAttention3d: B=4, C=128, D=16, H=W=64.
//   K0 prep  : 6 weight mats f32 -> bf16, pre-swizzled halved tables in ws
//   K1 qkv   : swapped-MFMA, reg-resident X frags, direct b64 stores
//   K2 attn  : per (b,c,d) 64x64; PV swapped -> direct b64 O stores
//   K3 tail  : a1+relu -> a2 (LDS chain, b64 writes) -> f swapped -> f32x4 stores

#define CCH 128
#define SPB 65536      // per-batch spatial = D*H*W
#define NBATCH 4
#define WTAB 16384     // elements per 128x128 weight table (two 8192 halves)

typedef float f32x4 __attribute__((ext_vector_type(4)));
typedef __bf16 bf16x8 __attribute__((ext_vector_type(8)));
typedef short s16x8 __attribute__((ext_vector_type(8)));
typedef unsigned short u16x8 __attribute__((ext_vector_type(8)));
typedef unsigned short u16x4 __attribute__((ext_vector_type(4)));
typedef unsigned int u32x2 __attribute__((ext_vector_type(2)));

// ---- MFMA wrapper: robust to builtin signature (v8i16 vs v8bf16) ----
template <typename T>
static __device__ __forceinline__ auto mfma_try(T a, T b, f32x4 c, int)
    -> decltype(__builtin_amdgcn_mfma_f32_16x16x32_bf16(a, b, c, 0, 0, 0)) {
  return __builtin_amdgcn_mfma_f32_16x16x32_bf16(a, b, c, 0, 0, 0);
}
template <typename T>
static __device__ __forceinline__ f32x4 mfma_try(T a, T b, f32x4 c, long) {
  return __builtin_amdgcn_mfma_f32_16x16x32_bf16(
      __builtin_bit_cast(bf16x8, a), __builtin_bit_cast(bf16x8, b), c, 0, 0, 0);
}
static __device__ __forceinline__ f32x4 MFMA16(u16x8 a, u16x8 b, f32x4 c) {
  return mfma_try(__builtin_bit_cast(s16x8, a), __builtin_bit_cast(s16x8, b), c, 0);
}

static __device__ __forceinline__ unsigned short f2b(float f) {
  return __builtin_bit_cast(unsigned short, (__bf16)f);
}
static __device__ __forceinline__ unsigned int pk2(float a, float b) {
  return (unsigned int)f2b(a) | ((unsigned int)f2b(b) << 16);
}

// async global->LDS, 16B per lane (linear dest, pre-swizzled source tables)
static __device__ __forceinline__ void glds16(const unsigned short* g,
                                              unsigned short* l) {
  __builtin_amdgcn_global_load_lds(
      (const __attribute__((address_space(1))) unsigned int*)g,
      (__attribute__((address_space(3))) unsigned int*)l, 16, 0, 0);
}

// lgkm-only barrier: LDS ordering without draining stores/glds (T4 pattern)
static __device__ __forceinline__ void bar_lgkm() {
  asm volatile("s_waitcnt lgkmcnt(0)" ::: "memory");
  __builtin_amdgcn_sched_barrier(0);
  __builtin_amdgcn_s_barrier();
  __builtin_amdgcn_sched_barrier(0);
}
// barrier draining all vmem (glds resident; no stores pending at call sites)
static __device__ __forceinline__ void bar_vm0() {
  asm volatile("s_waitcnt vmcnt(0)" ::: "memory");
  __builtin_amdgcn_sched_barrier(0);
  __builtin_amdgcn_s_barrier();
  __builtin_amdgcn_sched_barrier(0);
}
// counted: keep 16 newest (this conv's stores) in flight, drain older (glds)
static __device__ __forceinline__ void bar_vm16() {
  asm volatile("s_waitcnt vmcnt(16)" ::: "memory");
  __builtin_amdgcn_sched_barrier(0);
  __builtin_amdgcn_s_barrier();
  __builtin_amdgcn_sched_barrier(0);
}

// --- swizzles (element index), bijective per row ---
static __device__ __forceinline__ int swzc(int r, int c) {   // 128-col u16 tile
  int slot = ((c >> 3) ^ (r & 7) ^ ((r >> 3) & 15)) & 15;
  return r * 128 + slot * 8 + (c & 7);
}
static __device__ __forceinline__ int widx(int r, int c) {   // halved W table
  return (r & 64) * 128 + swzc(r & 63, c);
}
static __device__ __forceinline__ int swat(int w, int x) {   // 64-col attn tile
  int slot = ((x >> 3) ^ (w & 7) ^ ((w >> 3) & 7)) & 7;
  return w * 64 + slot * 8 + (x & 7);
}
static __device__ __forceinline__ int pix(int i, int j) {    // attn P tile
  int slot = ((j >> 3) ^ (((i >> 2) & 3) << 1)) & 7;
  return i * 64 + slot * 8 + (j & 7);
}

// ---------------------------------------------------------------------------
// K0: weights f32 -> bf16 into halved swizzled tables (rows 0-63 | 64-127).
// ---------------------------------------------------------------------------
__global__ __launch_bounds__(256) void prep_w_kernel(
    const float* __restrict__ Wq, const float* __restrict__ Wk,
    const float* __restrict__ Wv, const float* __restrict__ W1,
    const float* __restrict__ W2, const float* __restrict__ W3,
    unsigned short* __restrict__ out)
{
  const float* Ws[6] = {Wq, Wk, Wv, W1, W2, W3};
  const float* W = Ws[blockIdx.x];
  unsigned short* o = out + (size_t)blockIdx.x * WTAB;
  const int tid = threadIdx.x;
#pragma unroll
  for (int p = 0; p < 16; ++p) {
    const int base = p * 1024 + tid * 4;
    const int m = base >> 7;
    const int c0 = base & 127;
    f32x4 v = *(const f32x4*)&W[base];
    u16x4 u;
#pragma unroll
    for (int e = 0; e < 4; ++e) u[e] = f2b(v[e]);
    *(u16x4*)&o[widx(m, c0)] = u;
  }
}

// ---------------------------------------------------------------------------
// K1: fused QKV, swapped MFMA (D[s][o] per lane -> direct b64 stores).
// X^T frags persist in regs; W cycled through wb(16K) + xc[0:8K] via glds.
// ---------------------------------------------------------------------------
__global__ __launch_bounds__(256, 3) void qkv_kernel(
    const float* __restrict__ X, const unsigned short* __restrict__ Wbf,
    const float* __restrict__ Bq, const float* __restrict__ Bk,
    const float* __restrict__ Bv,
    unsigned short* __restrict__ Yq, unsigned short* __restrict__ Yk,
    unsigned short* __restrict__ Yv)
{
  __shared__ unsigned short xc[16384];   // X^T[s][c]; [0:8192] reused as W h1
  __shared__ unsigned short wb[8192];    // W h0 (o 0..63)
  __shared__ float bias_lds[3][128];

  const int tid  = threadIdx.x;
  const int wv   = tid >> 6;
  const int lane = tid & 63;
  const int lr   = lane & 15;
  const int lg   = lane >> 4;
  const int s0   = blockIdx.x * 128;
  const size_t xbase = (size_t)blockIdx.y * CCH * SPB;
  const int go = tid * 8;                // glds per-thread element offset

  if (tid < 128) {
    bias_lds[0][tid] = Bq[tid];
    bias_lds[1][tid] = Bk[tid];
    bias_lds[2][tid] = Bv[tid];
  }

  // ---- stage X^T: 2 c-rows x 32 s per thread; c-pair packed b32 ds writes ----
  {
    const int cp = tid >> 2;             // c-pair 0..63
    const int sq = tid & 3;              // s-quarter
    const float* xa = X + xbase + (size_t)(2 * cp) * SPB + s0 + sq * 32;
    const float* xb = xa + SPB;
    unsigned int* xc32 = (unsigned int*)xc;
#pragma unroll
    for (int i = 0; i < 8; ++i) {
      f32x4 a = *(const f32x4*)&xa[4 * i];
      f32x4 b = *(const f32x4*)&xb[4 * i];
#pragma unroll
      for (int e = 0; e < 4; ++e)
        xc32[swzc(sq * 32 + 4 * i + e, 2 * cp) >> 1] = pk2(a[e], b[e]);
    }
  }
  __syncthreads();   // S1: X^T staged

  // ---- A-frags (X^T rows), kept in regs for all three convs ----
  u16x8 afr[2][4];
#pragma unroll
  for (int sf = 0; sf < 2; ++sf)
#pragma unroll
    for (int ks = 0; ks < 4; ++ks)
      afr[sf][ks] = *(const u16x8*)&xc[swzc(wv * 32 + sf * 16 + lr, ks * 32 + lg * 8)];
  __syncthreads();   // S2: all frag reads done; xc[0:8192] reusable

  // ---- glds Wq: h0 -> wb, h1 -> xc[0:8192] ----
#pragma unroll
  for (int p = 0; p < 4; ++p) glds16(&Wbf[p * 2048 + go], &wb[p * 2048 + go]);
#pragma unroll
  for (int p = 0; p < 4; ++p) glds16(&Wbf[8192 + p * 2048 + go], &xc[p * 2048 + go]);
  __syncthreads();   // S3: Wq resident

#pragma unroll
  for (int ci = 0; ci < 3; ++ci) {
    // ---- GEMM: D[s][o], A = X^T frag, B = W frag ----
    f32x4 acc[2][8];
#pragma unroll
    for (int sf = 0; sf < 2; ++sf)
#pragma unroll
      for (int of = 0; of < 8; ++of) {
        f32x4 z = {0.f, 0.f, 0.f, 0.f};
        acc[sf][of] = z;
      }
#pragma unroll
    for (int ks = 0; ks < 4; ++ks) {
      const int k0 = ks * 32 + lg * 8;
#pragma unroll
      for (int of = 0; of < 8; ++of) {
        u16x8 bfr = (of < 4)
            ? *(const u16x8*)&wb[swzc(of * 16 + lr, k0)]
            : *(const u16x8*)&xc[swzc((of - 4) * 16 + lr, k0)];
        acc[0][of] = MFMA16(afr[0][ks], bfr, acc[0][of]);
        acc[1][of] = MFMA16(afr[1][ks], bfr, acc[1][of]);
      }
    }

    if (ci < 2) {
      bar_lgkm();    // all waves' W reads done -> regions reusable
      const unsigned short* Wn = Wbf + (size_t)(ci + 1) * WTAB;
#pragma unroll
      for (int p = 0; p < 4; ++p) glds16(&Wn[p * 2048 + go], &wb[p * 2048 + go]);
#pragma unroll
      for (int p = 0; p < 4; ++p) glds16(&Wn[8192 + p * 2048 + go], &xc[p * 2048 + go]);
      __builtin_amdgcn_sched_barrier(0);   // keep glds ahead of stores
    }

    // ---- epilogue: bias + cvt_pk, 16 direct b64 stores ----
    float bv8[8];
#pragma unroll
    for (int of = 0; of < 8; ++of) bv8[of] = bias_lds[ci][of * 16 + lr];
    unsigned short* Y = (ci == 0) ? Yq : (ci == 1) ? Yk : Yv;
    const int sb = s0 + wv * 32 + lg * 4;
#pragma unroll
    for (int sf = 0; sf < 2; ++sf)
#pragma unroll
      for (int of = 0; of < 8; ++of) {
        u32x2 pk;
        pk.x = pk2(acc[sf][of][0] + bv8[of], acc[sf][of][1] + bv8[of]);
        pk.y = pk2(acc[sf][of][2] + bv8[of], acc[sf][of][3] + bv8[of]);
        *(u32x2*)&Y[xbase + (size_t)(of * 16 + lr) * SPB + sb + sf * 16] = pk;
      }

    if (ci < 2) bar_vm16();  // drain 8 glds (oldest); 16 stores stay in flight
  }
}

// ---------------------------------------------------------------------------
// K2: attention per (b,c,d) 64x64 slice. PV swapped -> direct b64 O stores.
// ---------------------------------------------------------------------------
__global__ __launch_bounds__(256, 4) void attn64_kernel(
    const unsigned short* __restrict__ Q,
    const unsigned short* __restrict__ K,
    const unsigned short* __restrict__ V,
    unsigned short* __restrict__ O)
{
  __shared__ unsigned short qt[4096];   // Q^T[w][x]
  __shared__ unsigned short kt[4096];   // K^T[w][x]
  __shared__ unsigned short vt[4096];   // V^T[w][x]
  __shared__ unsigned short pbuf[4096]; // P rows (wave-private)

  const int tid  = threadIdx.x;
  const int wv   = tid >> 6;
  const int lane = tid & 63;
  const int lr   = lane & 15;
  const int lg   = lane >> 4;
  const size_t base = (size_t)blockIdx.x * 4096;

  // ---- stage transposed: 2 x-rows x 8 w per thread, b32 pair ds writes ----
  {
    const int x0 = (tid >> 3) * 2;
    const int w0 = (tid & 7) * 8;
    const size_t ga = base + (size_t)x0 * 64 + w0;
    u16x8 qa = *(const u16x8*)&Q[ga], qb = *(const u16x8*)&Q[ga + 64];
    u16x8 ka = *(const u16x8*)&K[ga], kb = *(const u16x8*)&K[ga + 64];
    u16x8 va = *(const u16x8*)&V[ga], vb = *(const u16x8*)&V[ga + 64];
    unsigned int* qt32 = (unsigned int*)qt;
    unsigned int* kt32 = (unsigned int*)kt;
    unsigned int* vt32 = (unsigned int*)vt;
#pragma unroll
    for (int e = 0; e < 8; ++e) {
      const int idx = swat(w0 + e, x0) >> 1;
      qt32[idx] = (unsigned int)qa[e] | ((unsigned int)qb[e] << 16);
      kt32[idx] = (unsigned int)ka[e] | ((unsigned int)kb[e] << 16);
      vt32[idx] = (unsigned int)va[e] | ((unsigned int)vb[e] << 16);
    }
  }
  __syncthreads();

  // ---- S = Q^T K : D[i][j], i = 4lg+r, j = 16nf+lr ----
  f32x4 sacc[4];
#pragma unroll
  for (int nf = 0; nf < 4; ++nf) { f32x4 z = {0.f, 0.f, 0.f, 0.f}; sacc[nf] = z; }
#pragma unroll
  for (int ks = 0; ks < 2; ++ks) {
    const int k0 = ks * 32 + lg * 8;
    u16x8 a = *(const u16x8*)&qt[swat(wv * 16 + lr, k0)];
#pragma unroll
    for (int nf = 0; nf < 4; ++nf) {
      u16x8 bb = *(const u16x8*)&kt[swat(nf * 16 + lr, k0)];
      sacc[nf] = MFMA16(a, bb, sacc[nf]);
    }
  }

  // ---- softmax over j; P -> pbuf (wave-private rows) ----
#pragma unroll
  for (int r = 0; r < 4; ++r) {
    float m = fmaxf(fmaxf(sacc[0][r], sacc[1][r]), fmaxf(sacc[2][r], sacc[3][r]));
    m = fmaxf(m, __shfl_xor(m, 1));
    m = fmaxf(m, __shfl_xor(m, 2));
    m = fmaxf(m, __shfl_xor(m, 4));
    m = fmaxf(m, __shfl_xor(m, 8));
    float sum = 0.f;
#pragma unroll
    for (int nf = 0; nf < 4; ++nf) {
      float p = __expf(sacc[nf][r] - m);
      sacc[nf][r] = p;
      sum += p;
    }
    sum += __shfl_xor(sum, 1);
    sum += __shfl_xor(sum, 2);
    sum += __shfl_xor(sum, 4);
    sum += __shfl_xor(sum, 8);
    const float inv = 1.f / sum;
    const int i = wv * 16 + lg * 4 + r;
#pragma unroll
    for (int nf = 0; nf < 4; ++nf)
      pbuf[pix(i, nf * 16 + lr)] = f2b(sacc[nf][r] * inv);
  }

  // ---- O = P V, SWAPPED: D[j][i] per lane -> i = 16wv+lr, j = 16nf+4lg+r ----
  f32x4 oacc[4];
#pragma unroll
  for (int nf = 0; nf < 4; ++nf) { f32x4 z = {0.f, 0.f, 0.f, 0.f}; oacc[nf] = z; }
#pragma unroll
  for (int ks = 0; ks < 2; ++ks) {
    const int k0 = ks * 32 + lg * 8;
    u16x8 a = *(const u16x8*)&pbuf[pix(wv * 16 + lr, k0)];
#pragma unroll
    for (int nf = 0; nf < 4; ++nf) {
      u16x8 bb = *(const u16x8*)&vt[swat(nf * 16 + lr, k0)];
      oacc[nf] = MFMA16(bb, a, oacc[nf]);   // swapped args
    }
  }

  // ---- direct b64 O stores: O[i*64 + j..j+3] ----
  {
    const size_t ib = base + (size_t)(16 * wv + lr) * 64 + lg * 4;
#pragma unroll
    for (int nf = 0; nf < 4; ++nf) {
      u32x2 pk;
      pk.x = pk2(oacc[nf][0], oacc[nf][1]);
      pk.y = pk2(oacc[nf][2], oacc[nf][3]);
      *(u32x2*)&O[ib + nf * 16] = pk;
    }
  }
}

// ---------------------------------------------------------------------------
// K3: tail a1+relu -> a2 -> f. Chain epi via b64 ds writes (wave-private
// rows); final GEMM swapped -> direct f32x4 stores.
// ---------------------------------------------------------------------------
__global__ __launch_bounds__(256, 2) void tail_kernel(
    const unsigned short* __restrict__ Xb, const unsigned short* __restrict__ Wbf,
    const float* __restrict__ B1, const float* __restrict__ B2,
    const float* __restrict__ B3, float* __restrict__ OUT)
{
  __shared__ unsigned short wl[16384];   // W full (halved-table image)
  __shared__ unsigned short xc[16384];   // chain tile [s][c]
  __shared__ float bias_lds[3][128];

  const int tid  = threadIdx.x;
  const int wv   = tid >> 6;
  const int lane = tid & 63;
  const int lr   = lane & 15;
  const int lg   = lane >> 4;
  const int s0   = blockIdx.x * 128;
  const size_t xbase = (size_t)blockIdx.y * CCH * SPB;
  const int go = tid * 8;

  // issue W1 glds first (overlaps staging)
#pragma unroll
  for (int p = 0; p < 8; ++p) glds16(&Wbf[p * 2048 + go], &wl[p * 2048 + go]);

  if (tid < 128) {
    bias_lds[0][tid] = B1[tid];
    bias_lds[1][tid] = B2[tid];
    bias_lds[2][tid] = B3[tid];
  }

  // ---- stage O^T (bf16): 2 c-rows x 32 s per thread, b32 pair writes ----
  {
    const int cp = tid >> 2;
    const int sq = tid & 3;
    const unsigned short* xa = Xb + xbase + (size_t)(2 * cp) * SPB + s0 + sq * 32;
    const unsigned short* xb = xa + SPB;
    unsigned int* xc32 = (unsigned int*)xc;
#pragma unroll
    for (int i = 0; i < 4; ++i) {
      u16x8 a = *(const u16x8*)&xa[8 * i];
      u16x8 b = *(const u16x8*)&xb[8 * i];
#pragma unroll
      for (int e = 0; e < 8; ++e)
        xc32[swzc(sq * 32 + 8 * i + e, 2 * cp) >> 1] =
            (unsigned int)a[e] | ((unsigned int)b[e] << 16);
    }
  }
  __syncthreads();   // S1: stage + W1 resident

  u16x8 bfr[2][4];
#pragma unroll
  for (int nf = 0; nf < 2; ++nf)
#pragma unroll
    for (int ks = 0; ks < 4; ++ks)
      bfr[nf][ks] = *(const u16x8*)&xc[swzc(wv * 32 + nf * 16 + lr, ks * 32 + lg * 8)];

  f32x4 acc[8][2];
  auto gemm_std = [&]() {    // unswapped: D[o][s] per lane
#pragma unroll
    for (int mf = 0; mf < 8; ++mf)
#pragma unroll
      for (int nf = 0; nf < 2; ++nf) {
        f32x4 z = {0.f, 0.f, 0.f, 0.f};
        acc[mf][nf] = z;
      }
#pragma unroll
    for (int ks = 0; ks < 4; ++ks) {
      const int k0 = ks * 32 + lg * 8;
#pragma unroll
      for (int mf = 0; mf < 8; ++mf) {
        u16x8 afr = *(const u16x8*)&wl[widx(mf * 16 + lr, k0)];
        acc[mf][0] = MFMA16(afr, bfr[0][ks], acc[mf][0]);
        acc[mf][1] = MFMA16(afr, bfr[1][ks], acc[mf][1]);
      }
    }
  };

  // chain epi: b64 writes into wave-private rows of xc, then frag refresh
  auto epi_chain = [&](int ci, bool relu) {
#pragma unroll
    for (int mf = 0; mf < 8; ++mf)
#pragma unroll
      for (int nf = 0; nf < 2; ++nf) {
        const int s = wv * 32 + nf * 16 + lr;
        const int c0 = mf * 16 + lg * 4;
        f32x4 bb = *(const f32x4*)&bias_lds[ci][c0];
        float v0 = acc[mf][nf][0] + bb[0];
        float v1 = acc[mf][nf][1] + bb[1];
        float v2 = acc[mf][nf][2] + bb[2];
        float v3 = acc[mf][nf][3] + bb[3];
        if (relu) {
          v0 = fmaxf(v0, 0.f); v1 = fmaxf(v1, 0.f);
          v2 = fmaxf(v2, 0.f); v3 = fmaxf(v3, 0.f);
        }
        u32x2 pk;
        pk.x = pk2(v0, v1);
        pk.y = pk2(v2, v3);
        *(u32x2*)&xc[swzc(s, c0)] = pk;
      }
#pragma unroll
    for (int nf = 0; nf < 2; ++nf)
#pragma unroll
      for (int ks = 0; ks < 4; ++ks)
        bfr[nf][ks] = *(const u16x8*)&xc[swzc(wv * 32 + nf * 16 + lr, ks * 32 + lg * 8)];
  };

#pragma unroll
  for (int j = 0; j < 2; ++j) {
    gemm_std();
    bar_lgkm();       // all waves' wl reads done
    const unsigned short* Wn = Wbf + (size_t)(j + 1) * WTAB;
#pragma unroll
    for (int p = 0; p < 8; ++p) glds16(&Wn[p * 2048 + go], &wl[p * 2048 + go]);
    epi_chain(j, j == 0);
    bar_vm0();        // next W resident (no stores pending)
  }

  // ---- final GEMM swapped: D[s][o] -> direct f32x4 stores ----
  {
    f32x4 acc3[2][8];
#pragma unroll
    for (int sf = 0; sf < 2; ++sf)
#pragma unroll
      for (int of = 0; of < 8; ++of) {
        f32x4 z = {0.f, 0.f, 0.f, 0.f};
        acc3[sf][of] = z;
      }
#pragma unroll
    for (int ks = 0; ks < 4; ++ks) {
      const int k0 = ks * 32 + lg * 8;
#pragma unroll
      for (int of = 0; of < 8; ++of) {
        u16x8 wfr = *(const u16x8*)&wl[widx(of * 16 + lr, k0)];
        acc3[0][of] = MFMA16(bfr[0][ks], wfr, acc3[0][of]);
        acc3[1][of] = MFMA16(bfr[1][ks], wfr, acc3[1][of]);
      }
    }
    const int sb = s0 + wv * 32 + lg * 4;
#pragma unroll
    for (int sf = 0; sf < 2; ++sf)
#pragma unroll
      for (int of = 0; of < 8; ++of) {
        const float b = bias_lds[2][of * 16 + lr];
        f32x4 v = acc3[sf][of];
        v[0] += b; v[1] += b; v[2] += b; v[3] += b;
        *(f32x4*)&OUT[xbase + (size_t)(of * 16 + lr) * SPB + sb + sf * 16] = v;
      }
  }
}

extern "C" void kernel_launch(void* const* d_in, const int* in_sizes, int n_in,
                              void* d_out, int out_size, void* d_ws, size_t ws_size,
                              hipStream_t stream) {
  const float* x   = (const float*)d_in[0];
  const float* Wq  = (const float*)d_in[1];  const float* bq  = (const float*)d_in[2];
  const float* Wk  = (const float*)d_in[3];  const float* bk  = (const float*)d_in[4];
  const float* Wv  = (const float*)d_in[5];  const float* bv  = (const float*)d_in[6];
  const float* Wa1 = (const float*)d_in[7];  const float* ba1 = (const float*)d_in[8];
  const float* Wa2 = (const float*)d_in[9];  const float* ba2 = (const float*)d_in[10];
  const float* Wf  = (const float*)d_in[11]; const float* bf_ = (const float*)d_in[12];

  // ws layout: q (67.1MB) then 6 bf16 weight tables (192KB).
  unsigned short* qb  = (unsigned short*)d_ws;
  unsigned short* wbf = qb + (size_t)NBATCH * CCH * SPB;
  // k,v packed into d_out (dead before final f32 write).
  unsigned short* kb = (unsigned short*)d_out;
  unsigned short* vb = kb + (size_t)NBATCH * CCH * SPB;

  dim3 grid(SPB / 128, NBATCH);

  prep_w_kernel<<<6, 256, 0, stream>>>(Wq, Wk, Wv, Wa1, Wa2, Wf, wbf);

  qkv_kernel<<<grid, 256, 0, stream>>>(x, wbf, bq, bk, bv, qb, kb, vb);

  attn64_kernel<<<NBATCH * CCH * 16, 256, 0, stream>>>(qb, kb, vb, qb);

  tail_kernel<<<grid, 256, 0, stream>>>(qb, wbf + (size_t)3 * WTAB,
                                        ba1, ba2, bf_, (float*)d_out);
}

// Round 7
// 177.338 us; speedup vs baseline: 1.7901x; 1.2348x over previous
//
#include <hip/hip_runtime.h>

// SelfAttention3d: B=4, C=128, D=16, H=W=64.
//   K0 prep  : 6 weight mats f32 -> bf16, pre-swizzled halved tables in ws
//   K1 qkv   : DRAM-locality blocking: 512 WGs x 512 thr, N=512 strip/WG,
//              all 3 W tables LDS-resident, X reg-prefetch, 256B-burst stores
//   K2 attn  : per (b,c,d) 64x64; PV swapped -> direct b64 O stores
//   K3 tail  : a1+relu -> a2 (LDS chain) -> f swapped -> f32x4 stores

#define CCH 128
#define SPB 65536      // per-batch spatial = D*H*W
#define NBATCH 4
#define WTAB 16384     // elements per 128x128 weight table (two 8192 halves)

typedef float f32x4 __attribute__((ext_vector_type(4)));
typedef __bf16 bf16x8 __attribute__((ext_vector_type(8)));
typedef short s16x8 __attribute__((ext_vector_type(8)));
typedef unsigned short u16x8 __attribute__((ext_vector_type(8)));
typedef unsigned short u16x4 __attribute__((ext_vector_type(4)));
typedef unsigned int u32x2 __attribute__((ext_vector_type(2)));

// ---- MFMA wrapper: robust to builtin signature (v8i16 vs v8bf16) ----
template <typename T>
static __device__ __forceinline__ auto mfma_try(T a, T b, f32x4 c, int)
    -> decltype(__builtin_amdgcn_mfma_f32_16x16x32_bf16(a, b, c, 0, 0, 0)) {
  return __builtin_amdgcn_mfma_f32_16x16x32_bf16(a, b, c, 0, 0, 0);
}
template <typename T>
static __device__ __forceinline__ f32x4 mfma_try(T a, T b, f32x4 c, long) {
  return __builtin_amdgcn_mfma_f32_16x16x32_bf16(
      __builtin_bit_cast(bf16x8, a), __builtin_bit_cast(bf16x8, b), c, 0, 0, 0);
}
static __device__ __forceinline__ f32x4 MFMA16(u16x8 a, u16x8 b, f32x4 c) {
  return mfma_try(__builtin_bit_cast(s16x8, a), __builtin_bit_cast(s16x8, b), c, 0);
}

static __device__ __forceinline__ unsigned short f2b(float f) {
  return __builtin_bit_cast(unsigned short, (__bf16)f);
}
static __device__ __forceinline__ unsigned int pk2(float a, float b) {
  return (unsigned int)f2b(a) | ((unsigned int)f2b(b) << 16);
}

// async global->LDS, 16B per lane (linear dest, pre-swizzled source tables)
static __device__ __forceinline__ void glds16(const unsigned short* g,
                                              unsigned short* l) {
  __builtin_amdgcn_global_load_lds(
      (const __attribute__((address_space(1))) unsigned int*)g,
      (__attribute__((address_space(3))) unsigned int*)l, 16, 0, 0);
}

// lgkm-only barrier: LDS ordering without draining stores/glds (T4 pattern)
static __device__ __forceinline__ void bar_lgkm() {
  asm volatile("s_waitcnt lgkmcnt(0)" ::: "memory");
  __builtin_amdgcn_sched_barrier(0);
  __builtin_amdgcn_s_barrier();
  __builtin_amdgcn_sched_barrier(0);
}
static __device__ __forceinline__ void bar_vm0() {
  asm volatile("s_waitcnt vmcnt(0)" ::: "memory");
  __builtin_amdgcn_sched_barrier(0);
  __builtin_amdgcn_s_barrier();
  __builtin_amdgcn_sched_barrier(0);
}

// --- swizzles (element index), bijective per row ---
static __device__ __forceinline__ int swzc(int r, int c) {   // 128-col u16 tile
  int slot = ((c >> 3) ^ (r & 7) ^ ((r >> 3) & 15)) & 15;
  return r * 128 + slot * 8 + (c & 7);
}
static __device__ __forceinline__ int widx(int r, int c) {   // halved W table
  return (r & 64) * 128 + swzc(r & 63, c);
}
// C repack tile [o][s] u16 (qkv): b64 epilogue writes + 256B readback rows.
static __device__ __forceinline__ int cbix(int o, int s) {
  int slot = ((s >> 3) ^ (o & 15)) & 15;
  return o * 128 + slot * 8 + (s & 7);
}
static __device__ __forceinline__ int swat(int w, int x) {   // 64-col attn tile
  int slot = ((x >> 3) ^ (w & 7) ^ ((w >> 3) & 7)) & 7;
  return w * 64 + slot * 8 + (x & 7);
}
static __device__ __forceinline__ int pix(int i, int j) {    // attn P tile
  int slot = ((j >> 3) ^ (((i >> 2) & 3) << 1)) & 7;
  return i * 64 + slot * 8 + (j & 7);
}

// ---------------------------------------------------------------------------
// K0: weights f32 -> bf16 into halved swizzled tables (rows 0-63 | 64-127).
// ---------------------------------------------------------------------------
__global__ __launch_bounds__(256) void prep_w_kernel(
    const float* __restrict__ Wq, const float* __restrict__ Wk,
    const float* __restrict__ Wv, const float* __restrict__ W1,
    const float* __restrict__ W2, const float* __restrict__ W3,
    unsigned short* __restrict__ out)
{
  const float* Ws[6] = {Wq, Wk, Wv, W1, W2, W3};
  const float* W = Ws[blockIdx.x];
  unsigned short* o = out + (size_t)blockIdx.x * WTAB;
  const int tid = threadIdx.x;
#pragma unroll
  for (int p = 0; p < 16; ++p) {
    const int base = p * 1024 + tid * 4;
    const int m = base >> 7;
    const int c0 = base & 127;
    f32x4 v = *(const f32x4*)&W[base];
    u16x4 u;
#pragma unroll
    for (int e = 0; e < 4; ++e) u[e] = f2b(v[e]);
    *(u16x4*)&o[widx(m, c0)] = u;
  }
}

// ---------------------------------------------------------------------------
// K1: fused QKV. One WG per 512-spatial strip (512 WGs, 512 thr, 1 WG/CU).
// W tables (96KB) LDS-resident whole kernel; X sub-tiles (128 s) stream
// through a 32KB buffer time-shared with the C repack; next X sub-tile is
// register-prefetched under the GEMMs. Stores: 4 rows x 256B per wave-instr.
// ---------------------------------------------------------------------------
__global__ __launch_bounds__(512, 2) void qkv_kernel(
    const float* __restrict__ X, const unsigned short* __restrict__ Wbf,
    const float* __restrict__ Bq, const float* __restrict__ Bk,
    const float* __restrict__ Bv,
    unsigned short* __restrict__ Yq, unsigned short* __restrict__ Yk,
    unsigned short* __restrict__ Yv)
{
  __shared__ unsigned short wt[3 * WTAB];  // 96KB: Wq,Wk,Wv swizzled images
  __shared__ unsigned short xb[WTAB];      // 32KB: X^T stage, then C repack

  const int tid  = threadIdx.x;
  const int wv   = tid >> 6;
  const int lane = tid & 63;
  const int lr   = lane & 15;
  const int lg   = lane >> 4;
  const int sbase = blockIdx.x * 512;
  const size_t xoff = (size_t)blockIdx.y * CCH * SPB;

  // ---- issue all W glds up front (12 x 16B per thread; drained by S0) ----
  const int go = tid * 8;
#pragma unroll
  for (int t = 0; t < 3; ++t)
#pragma unroll
    for (int p = 0; p < 4; ++p)
      glds16(&Wbf[t * WTAB + p * 4096 + go], &wt[t * WTAB + p * 4096 + go]);

  // ---- bias -> regs (o = of*16+lr per lane) ----
  float bq_v[8], bk_v[8], bv_v[8];
#pragma unroll
  for (int of = 0; of < 8; ++of) {
    bq_v[of] = Bq[of * 16 + lr];
    bk_v[of] = Bk[of * 16 + lr];
    bv_v[of] = Bv[of * 16 + lr];
  }

  // ---- staging geometry: thread owns c-pair (c0,c0+1), s-range sb8+[0,4) x4 ----
  const int c0  = (tid >> 3) * 2;
  const int sb8 = (tid & 7) * 4;
  const float* xrow = X + xoff + (size_t)c0 * SPB + sbase;
  unsigned int* xb32 = (unsigned int*)xb;

  f32x4 xr[8];
#pragma unroll
  for (int i = 0; i < 4; ++i) {
    xr[i]     = *(const f32x4*)&xrow[sb8 + 32 * i];
    xr[4 + i] = *(const f32x4*)&xrow[SPB + sb8 + 32 * i];
  }
  // cvt + stage sub-tile 0 (vmcnt in-order: waiting on xr drains W glds too)
#pragma unroll
  for (int i = 0; i < 4; ++i)
#pragma unroll
    for (int e = 0; e < 4; ++e)
      xb32[swzc(sb8 + 32 * i + e, c0) >> 1] = pk2(xr[i][e], xr[4 + i][e]);
  __syncthreads();   // S0: X0 staged, W resident

#pragma unroll
  for (int si = 0; si < 4; ++si) {
    const int sg = sbase + si * 128;

    // ---- A-frags for this sub-tile -> regs ----
    u16x8 afr[4];
#pragma unroll
    for (int ks = 0; ks < 4; ++ks)
      afr[ks] = *(const u16x8*)&xb[swzc(wv * 16 + lr, ks * 32 + lg * 8)];

    // ---- T14: issue next X sub-tile loads (consumed at loop tail) ----
    if (si < 3) {
      const float* xn = xrow + (si + 1) * 128;
#pragma unroll
      for (int i = 0; i < 4; ++i) {
        xr[i]     = *(const f32x4*)&xn[sb8 + 32 * i];
        xr[4 + i] = *(const f32x4*)&xn[SPB + sb8 + 32 * i];
      }
    }
    bar_lgkm();   // all afr reads done; xb free for C repack

    // ---- one conv: GEMM from resident W, repack, 256B-burst stores ----
    auto conv = [&](int t, const float (&b8)[8], unsigned short* __restrict__ Y) {
      f32x4 acc[8];
#pragma unroll
      for (int of = 0; of < 8; ++of) {
        f32x4 z = {0.f, 0.f, 0.f, 0.f};
        acc[of] = z;
      }
#pragma unroll
      for (int ks = 0; ks < 4; ++ks) {
        const int k0 = ks * 32 + lg * 8;
#pragma unroll
        for (int of = 0; of < 8; ++of) {
          u16x8 wfr = *(const u16x8*)&wt[t * WTAB + widx(of * 16 + lr, k0)];
          acc[of] = MFMA16(afr[ks], wfr, acc[of]);   // D[s][o] per lane
        }
      }
      // epilogue: s = wv*16+lg*4+r (4 consecutive), o = of*16+lr -> b64 writes
#pragma unroll
      for (int of = 0; of < 8; ++of) {
        const float b = b8[of];
        u32x2 pk;
        pk.x = pk2(acc[of][0] + b, acc[of][1] + b);
        pk.y = pk2(acc[of][2] + b, acc[of][3] + b);
        *(u32x2*)&xb[cbix(of * 16 + lr, wv * 16 + lg * 4)] = pk;
      }
      bar_lgkm();   // repack visible
      // readback: 16 lanes/row -> 4 rows x 256B contiguous per wave-instr
#pragma unroll
      for (int p = 0; p < 4; ++p) {
        const int row = p * 32 + (tid >> 4);
        const int sc  = (tid & 15) * 8;
        u16x8 v = *(const u16x8*)&xb[cbix(row, sc)];
        *(u16x8*)&Y[xoff + (size_t)row * SPB + sg + sc] = v;
      }
      bar_lgkm();   // readback reads done; xb reusable (stores stay in flight)
    };

    conv(0, bq_v, Yq);
    conv(1, bk_v, Yk);
    conv(2, bv_v, Yv);

    // ---- stage next sub-tile from prefetched regs ----
    if (si < 3) {
#pragma unroll
      for (int i = 0; i < 4; ++i)
#pragma unroll
        for (int e = 0; e < 4; ++e)
          xb32[swzc(sb8 + 32 * i + e, c0) >> 1] = pk2(xr[i][e], xr[4 + i][e]);
      __syncthreads();
    }
  }
}

// ---------------------------------------------------------------------------
// K2: attention per (b,c,d) 64x64 slice (unchanged from round 6).
// ---------------------------------------------------------------------------
__global__ __launch_bounds__(256, 4) void attn64_kernel(
    const unsigned short* __restrict__ Q,
    const unsigned short* __restrict__ K,
    const unsigned short* __restrict__ V,
    unsigned short* __restrict__ O)
{
  __shared__ unsigned short qt[4096];   // Q^T[w][x]
  __shared__ unsigned short kt[4096];   // K^T[w][x]
  __shared__ unsigned short vt[4096];   // V^T[w][x]
  __shared__ unsigned short pbuf[4096]; // P rows (wave-private)

  const int tid  = threadIdx.x;
  const int wv   = tid >> 6;
  const int lane = tid & 63;
  const int lr   = lane & 15;
  const int lg   = lane >> 4;
  const size_t base = (size_t)blockIdx.x * 4096;

  {
    const int x0 = (tid >> 3) * 2;
    const int w0 = (tid & 7) * 8;
    const size_t ga = base + (size_t)x0 * 64 + w0;
    u16x8 qa = *(const u16x8*)&Q[ga], qb = *(const u16x8*)&Q[ga + 64];
    u16x8 ka = *(const u16x8*)&K[ga], kb = *(const u16x8*)&K[ga + 64];
    u16x8 va = *(const u16x8*)&V[ga], vb = *(const u16x8*)&V[ga + 64];
    unsigned int* qt32 = (unsigned int*)qt;
    unsigned int* kt32 = (unsigned int*)kt;
    unsigned int* vt32 = (unsigned int*)vt;
#pragma unroll
    for (int e = 0; e < 8; ++e) {
      const int idx = swat(w0 + e, x0) >> 1;
      qt32[idx] = (unsigned int)qa[e] | ((unsigned int)qb[e] << 16);
      kt32[idx] = (unsigned int)ka[e] | ((unsigned int)kb[e] << 16);
      vt32[idx] = (unsigned int)va[e] | ((unsigned int)vb[e] << 16);
    }
  }
  __syncthreads();

  f32x4 sacc[4];
#pragma unroll
  for (int nf = 0; nf < 4; ++nf) { f32x4 z = {0.f, 0.f, 0.f, 0.f}; sacc[nf] = z; }
#pragma unroll
  for (int ks = 0; ks < 2; ++ks) {
    const int k0 = ks * 32 + lg * 8;
    u16x8 a = *(const u16x8*)&qt[swat(wv * 16 + lr, k0)];
#pragma unroll
    for (int nf = 0; nf < 4; ++nf) {
      u16x8 bb = *(const u16x8*)&kt[swat(nf * 16 + lr, k0)];
      sacc[nf] = MFMA16(a, bb, sacc[nf]);
    }
  }

#pragma unroll
  for (int r = 0; r < 4; ++r) {
    float m = fmaxf(fmaxf(sacc[0][r], sacc[1][r]), fmaxf(sacc[2][r], sacc[3][r]));
    m = fmaxf(m, __shfl_xor(m, 1));
    m = fmaxf(m, __shfl_xor(m, 2));
    m = fmaxf(m, __shfl_xor(m, 4));
    m = fmaxf(m, __shfl_xor(m, 8));
    float sum = 0.f;
#pragma unroll
    for (int nf = 0; nf < 4; ++nf) {
      float p = __expf(sacc[nf][r] - m);
      sacc[nf][r] = p;
      sum += p;
    }
    sum += __shfl_xor(sum, 1);
    sum += __shfl_xor(sum, 2);
    sum += __shfl_xor(sum, 4);
    sum += __shfl_xor(sum, 8);
    const float inv = 1.f / sum;
    const int i = wv * 16 + lg * 4 + r;
#pragma unroll
    for (int nf = 0; nf < 4; ++nf)
      pbuf[pix(i, nf * 16 + lr)] = f2b(sacc[nf][r] * inv);
  }

  f32x4 oacc[4];
#pragma unroll
  for (int nf = 0; nf < 4; ++nf) { f32x4 z = {0.f, 0.f, 0.f, 0.f}; oacc[nf] = z; }
#pragma unroll
  for (int ks = 0; ks < 2; ++ks) {
    const int k0 = ks * 32 + lg * 8;
    u16x8 a = *(const u16x8*)&pbuf[pix(wv * 16 + lr, k0)];
#pragma unroll
    for (int nf = 0; nf < 4; ++nf) {
      u16x8 bb = *(const u16x8*)&vt[swat(nf * 16 + lr, k0)];
      oacc[nf] = MFMA16(bb, a, oacc[nf]);   // swapped args
    }
  }

  {
    const size_t ib = base + (size_t)(16 * wv + lr) * 64 + lg * 4;
#pragma unroll
    for (int nf = 0; nf < 4; ++nf) {
      u32x2 pk;
      pk.x = pk2(oacc[nf][0], oacc[nf][1]);
      pk.y = pk2(oacc[nf][2], oacc[nf][3]);
      *(u32x2*)&O[ib + nf * 16] = pk;
    }
  }
}

// ---------------------------------------------------------------------------
// K3: tail a1+relu -> a2 -> f (unchanged from round 6).
// ---------------------------------------------------------------------------
__global__ __launch_bounds__(256, 2) void tail_kernel(
    const unsigned short* __restrict__ Xb, const unsigned short* __restrict__ Wbf,
    const float* __restrict__ B1, const float* __restrict__ B2,
    const float* __restrict__ B3, float* __restrict__ OUT)
{
  __shared__ unsigned short wl[16384];   // W full (halved-table image)
  __shared__ unsigned short xc[16384];   // chain tile [s][c]
  __shared__ float bias_lds[3][128];

  const int tid  = threadIdx.x;
  const int wv   = tid >> 6;
  const int lane = tid & 63;
  const int lr   = lane & 15;
  const int lg   = lane >> 4;
  const int s0   = blockIdx.x * 128;
  const size_t xbase = (size_t)blockIdx.y * CCH * SPB;
  const int go = tid * 8;

#pragma unroll
  for (int p = 0; p < 8; ++p) glds16(&Wbf[p * 2048 + go], &wl[p * 2048 + go]);

  if (tid < 128) {
    bias_lds[0][tid] = B1[tid];
    bias_lds[1][tid] = B2[tid];
    bias_lds[2][tid] = B3[tid];
  }

  {
    const int cp = tid >> 2;
    const int sq = tid & 3;
    const unsigned short* xa = Xb + xbase + (size_t)(2 * cp) * SPB + s0 + sq * 32;
    const unsigned short* xb = xa + SPB;
    unsigned int* xc32 = (unsigned int*)xc;
#pragma unroll
    for (int i = 0; i < 4; ++i) {
      u16x8 a = *(const u16x8*)&xa[8 * i];
      u16x8 b = *(const u16x8*)&xb[8 * i];
#pragma unroll
      for (int e = 0; e < 8; ++e)
        xc32[swzc(sq * 32 + 8 * i + e, 2 * cp) >> 1] =
            (unsigned int)a[e] | ((unsigned int)b[e] << 16);
    }
  }
  __syncthreads();   // S1: stage + W1 resident

  u16x8 bfr[2][4];
#pragma unroll
  for (int nf = 0; nf < 2; ++nf)
#pragma unroll
    for (int ks = 0; ks < 4; ++ks)
      bfr[nf][ks] = *(const u16x8*)&xc[swzc(wv * 32 + nf * 16 + lr, ks * 32 + lg * 8)];

  f32x4 acc[8][2];
  auto gemm_std = [&]() {
#pragma unroll
    for (int mf = 0; mf < 8; ++mf)
#pragma unroll
      for (int nf = 0; nf < 2; ++nf) {
        f32x4 z = {0.f, 0.f, 0.f, 0.f};
        acc[mf][nf] = z;
      }
#pragma unroll
    for (int ks = 0; ks < 4; ++ks) {
      const int k0 = ks * 32 + lg * 8;
#pragma unroll
      for (int mf = 0; mf < 8; ++mf) {
        u16x8 afr = *(const u16x8*)&wl[widx(mf * 16 + lr, k0)];
        acc[mf][0] = MFMA16(afr, bfr[0][ks], acc[mf][0]);
        acc[mf][1] = MFMA16(afr, bfr[1][ks], acc[mf][1]);
      }
    }
  };

  auto epi_chain = [&](int ci, bool relu) {
#pragma unroll
    for (int mf = 0; mf < 8; ++mf)
#pragma unroll
      for (int nf = 0; nf < 2; ++nf) {
        const int s = wv * 32 + nf * 16 + lr;
        const int c0 = mf * 16 + lg * 4;
        f32x4 bb = *(const f32x4*)&bias_lds[ci][c0];
        float v0 = acc[mf][nf][0] + bb[0];
        float v1 = acc[mf][nf][1] + bb[1];
        float v2 = acc[mf][nf][2] + bb[2];
        float v3 = acc[mf][nf][3] + bb[3];
        if (relu) {
          v0 = fmaxf(v0, 0.f); v1 = fmaxf(v1, 0.f);
          v2 = fmaxf(v2, 0.f); v3 = fmaxf(v3, 0.f);
        }
        u32x2 pk;
        pk.x = pk2(v0, v1);
        pk.y = pk2(v2, v3);
        *(u32x2*)&xc[swzc(s, c0)] = pk;
      }
#pragma unroll
    for (int nf = 0; nf < 2; ++nf)
#pragma unroll
      for (int ks = 0; ks < 4; ++ks)
        bfr[nf][ks] = *(const u16x8*)&xc[swzc(wv * 32 + nf * 16 + lr, ks * 32 + lg * 8)];
  };

#pragma unroll
  for (int j = 0; j < 2; ++j) {
    gemm_std();
    bar_lgkm();
    const unsigned short* Wn = Wbf + (size_t)(j + 1) * WTAB;
#pragma unroll
    for (int p = 0; p < 8; ++p) glds16(&Wn[p * 2048 + go], &wl[p * 2048 + go]);
    epi_chain(j, j == 0);
    bar_vm0();
  }

  {
    f32x4 acc3[2][8];
#pragma unroll
    for (int sf = 0; sf < 2; ++sf)
#pragma unroll
      for (int of = 0; of < 8; ++of) {
        f32x4 z = {0.f, 0.f, 0.f, 0.f};
        acc3[sf][of] = z;
      }
#pragma unroll
    for (int ks = 0; ks < 4; ++ks) {
      const int k0 = ks * 32 + lg * 8;
#pragma unroll
      for (int of = 0; of < 8; ++of) {
        u16x8 wfr = *(const u16x8*)&wl[widx(of * 16 + lr, k0)];
        acc3[0][of] = MFMA16(bfr[0][ks], wfr, acc3[0][of]);
        acc3[1][of] = MFMA16(bfr[1][ks], wfr, acc3[1][of]);
      }
    }
    const int sb = s0 + wv * 32 + lg * 4;
#pragma unroll
    for (int sf = 0; sf < 2; ++sf)
#pragma unroll
      for (int of = 0; of < 8; ++of) {
        const float b = bias_lds[2][of * 16 + lr];
        f32x4 v = acc3[sf][of];
        v[0] += b; v[1] += b; v[2] += b; v[3] += b;
        *(f32x4*)&OUT[xbase + (size_t)(of * 16 + lr) * SPB + sb + sf * 16] = v;
      }
  }
}

extern "C" void kernel_launch(void* const* d_in, const int* in_sizes, int n_in,
                              void* d_out, int out_size, void* d_ws, size_t ws_size,
                              hipStream_t stream) {
  const float* x   = (const float*)d_in[0];
  const float* Wq  = (const float*)d_in[1];  const float* bq  = (const float*)d_in[2];
  const float* Wk  = (const float*)d_in[3];  const float* bk  = (const float*)d_in[4];
  const float* Wv  = (const float*)d_in[5];  const float* bv  = (const float*)d_in[6];
  const float* Wa1 = (const float*)d_in[7];  const float* ba1 = (const float*)d_in[8];
  const float* Wa2 = (const float*)d_in[9];  const float* ba2 = (const float*)d_in[10];
  const float* Wf  = (const float*)d_in[11]; const float* bf_ = (const float*)d_in[12];

  // ws layout: q (67.1MB) then 6 bf16 weight tables (192KB).
  unsigned short* qb  = (unsigned short*)d_ws;
  unsigned short* wbf = qb + (size_t)NBATCH * CCH * SPB;
  // k,v packed into d_out (dead before final f32 write).
  unsigned short* kb = (unsigned short*)d_out;
  unsigned short* vb = kb + (size_t)NBATCH * CCH * SPB;

  prep_w_kernel<<<6, 256, 0, stream>>>(Wq, Wk, Wv, Wa1, Wa2, Wf, wbf);

  qkv_kernel<<<dim3(SPB / 512, NBATCH), 512, 0, stream>>>(
      x, wbf, bq, bk, bv, qb, kb, vb);

  attn64_kernel<<<NBATCH * CCH * 16, 256, 0, stream>>>(qb, kb, vb, qb);

  tail_kernel<<<dim3(SPB / 128, NBATCH), 256, 0, stream>>>(
      qb, wbf + (size_t)3 * WTAB, ba1, ba2, bf_, (float*)d_out);
}